// Round 1
// baseline (4613.121 us; speedup 1.0000x reference)
//
#include <hip/hip_runtime.h>

typedef unsigned short u16;
typedef unsigned int   u32;
typedef __attribute__((ext_vector_type(8))) short bh8;
typedef __attribute__((ext_vector_type(4))) float f4;

constexpr int BATCH = 8, HIDN = 1024, NHEAD = 8, HD = 256, NLAY = 18, DMLP = 4096;
constexpr int AHOR = 50, ADIMN = 32, PFXN = 1037, SEQN = 1087, NSTR = 17, MR = 400, MP = 512;
constexpr float EPSV = 1e-6f, NEGV = -2.3819763e38f, QSCALE = 0.0625f;

static __device__ __forceinline__ u16 f2bf(float x){
  union{float f; u32 u;} v; v.f = x;
  u32 r = (v.u + 0x7FFFu + ((v.u >> 16) & 1u)) >> 16;
  return (u16)r;
}
static __device__ __forceinline__ float bf2f(u16 u){
  union{u32 u; float f;} v; v.u = ((u32)u) << 16; return v.f;
}
static __device__ __forceinline__ u32 pack2(float a, float b){
  return (u32)f2bf(a) | ((u32)f2bf(b) << 16);
}
static __device__ __forceinline__ f4 MFMA(bh8 a, bh8 b, f4 c){
  return __builtin_amdgcn_mfma_f32_16x16x32_bf16(a, b, c, 0, 0, 0);
}
static __device__ __forceinline__ float siluf_(float x){ return x / (1.f + __expf(-x)); }
static __device__ __forceinline__ float geluf_(float x){
  float y = 0.7978845608028654f * (x + 0.044715f * x * x * x);
  float e = __expf(2.f * y);
  return 0.5f * x * (2.f - 2.f / (e + 1.f));
}

// ---------------- prep: temb, offs, rope tables ----------------
__global__ void k_prep(const int* __restrict__ mask, const float* __restrict__ ts,
                       float* __restrict__ temb, int* __restrict__ offs,
                       float* __restrict__ ropec, float* __restrict__ ropes)
{
  int t = threadIdx.x;
  if (t < BATCH){
    int s = 0; const int* mp = mask + t * PFXN;
    for (int k = 0; k < PFXN; ++k) s += (mp[k] != 0);
    offs[t] = s;
  }
  for (int i = t; i < BATCH * 512; i += 256){
    int b = i >> 9, j = i & 511;
    float frac = (float)j * (1.0f / 511.0f);
    float period = 0.004f * __expf(frac * 6.907755278982137f); // ln(1000)
    float arg = (6.283185307179586f / period) * ts[b];
    float s, c; sincosf(arg, &s, &c);
    temb[b * HIDN + j] = s;
    temb[b * HIDN + 512 + j] = c;
  }
  __syncthreads();
  for (int i = t; i < BATCH * AHOR * 128; i += 256){
    int d = i & 127, bt = i >> 7, b = bt / AHOR, tt = bt % AHOR;
    float inv = __expf(-((float)d * (1.f / 128.f)) * 9.210340371976184f); // ln(10000)
    float arg = (float)(offs[b] + tt) * inv;
    float s, c; sincosf(arg, &s, &c);
    ropec[i] = c; ropes[i] = s;
  }
}

// ---------------- tiny M=8 GEMM (1024x1024) + silu ----------------
__global__ void k_tproj(const float* __restrict__ X, const float* __restrict__ W,
                        const float* __restrict__ bias, float* __restrict__ out)
{
  __shared__ float xs[BATCH * HIDN];
  __shared__ float red[BATCH][8][32];
  int t = threadIdx.x;
  for (int i = t; i < BATCH * HIDN; i += 256) xs[i] = X[i];
  __syncthreads();
  int c = t & 31, kp = t >> 5;
  int c0 = blockIdx.x * 32;
  float acc[BATCH];
  #pragma unroll
  for (int b = 0; b < BATCH; ++b) acc[b] = 0.f;
  for (int k = kp * 128; k < kp * 128 + 128; ++k){
    float w = W[(size_t)k * HIDN + c0 + c];
    #pragma unroll
    for (int b = 0; b < BATCH; ++b) acc[b] += xs[b * HIDN + k] * w;
  }
  #pragma unroll
  for (int b = 0; b < BATCH; ++b) red[b][kp][c] = acc[b];
  __syncthreads();
  int b2 = t >> 5, c2 = t & 31;
  float s = bias[c0 + c2];
  #pragma unroll
  for (int kp2 = 0; kp2 < 8; ++kp2) s += red[b2][kp2][c2];
  out[b2 * HIDN + c0 + c2] = siluf_(s);
}

// ---------------- ada: cond @ {A1|A2|Af} -> scale/shift/gate for all layers ----------------
__global__ void k_ada(const float* __restrict__ cond, const float* __restrict__ A1,
                      const float* __restrict__ A2, const float* __restrict__ Af,
                      float* __restrict__ out)
{
  __shared__ float cs[BATCH * HIDN];
  int t = threadIdx.x; // 128
  for (int i = t; i < BATCH * HIDN; i += 128) cs[i] = cond[i];
  __syncthreads();
  int y = blockIdx.y; // 0..36
  const float* A = (y < NLAY) ? (A1 + (size_t)y * HIDN * 3072)
                  : (y < 2 * NLAY) ? (A2 + (size_t)(y - NLAY) * HIDN * 3072) : Af;
  int n = blockIdx.x * 128 + t; // 0..3071
  float acc[BATCH];
  #pragma unroll
  for (int b = 0; b < BATCH; ++b) acc[b] = 0.f;
  const float* ap = A + n;
  for (int k = 0; k < HIDN; ++k){
    float a = ap[(size_t)k * 3072];
    #pragma unroll
    for (int b = 0; b < BATCH; ++b) acc[b] += cs[b * HIDN + k] * a;
  }
  float* o = out + ((size_t)y * 3 + (n >> 10)) * BATCH * HIDN + (n & 1023);
  #pragma unroll
  for (int b = 0; b < BATCH; ++b) o[b * HIDN] = acc[b];
}

// ---------------- h0 = x_t @ W_act_in + b ----------------
__global__ void k_hin(const float* __restrict__ xt, const float* __restrict__ W,
                      const float* __restrict__ bias, float* __restrict__ h)
{
  int r = blockIdx.x; // 0..399
  int t = threadIdx.x; int c0 = t * 4;
  __shared__ float xs[ADIMN];
  if (t < ADIMN) xs[t] = xt[r * ADIMN + t];
  __syncthreads();
  float a0 = bias[c0], a1 = bias[c0+1], a2 = bias[c0+2], a3 = bias[c0+3];
  for (int k = 0; k < ADIMN; ++k){
    float x = xs[k];
    const float* wp = W + k * HIDN + c0;
    a0 += x * wp[0]; a1 += x * wp[1]; a2 += x * wp[2]; a3 += x * wp[3];
  }
  float* hp = h + (size_t)r * HIDN + c0;
  hp[0] = a0; hp[1] = a1; hp[2] = a2; hp[3] = a3;
}

// ---------------- residual + RMS + AdaNorm -> fragA bf16 ----------------
// mode 0: norm(base) only. mode 1: h1 = base + gate*sum4(parts); norm -> fragA; h1 -> outres.
// mode 2: same as 1 (h = h1 + gate*sum4(parts)).
__global__ void k_resnorm(int mode,
    const float* __restrict__ base, const u16* __restrict__ parts,
    const float* __restrict__ gate, const float* __restrict__ sc,
    const float* __restrict__ sh, float* __restrict__ outres,
    u16* __restrict__ fragA)
{
  __shared__ float redl[4];
  int t = threadIdx.x;
  int c = t * 4;
  for (int i = 0; i < 4; ++i){
    int r = blockIdx.x * 4 + i;
    bool live = (r < MR);
    float v0 = 0, v1 = 0, v2 = 0, v3 = 0;
    int b = live ? (r / AHOR) : 0;
    if (live){
      const float* bp = base + (size_t)r * HIDN + c;
      v0 = bp[0]; v1 = bp[1]; v2 = bp[2]; v3 = bp[3];
      if (mode){
        float s0 = 0, s1 = 0, s2 = 0, s3 = 0;
        #pragma unroll
        for (int p = 0; p < 4; ++p){
          const u16* pp = parts + ((size_t)p * MP + r) * HIDN + c;
          s0 += bf2f(pp[0]); s1 += bf2f(pp[1]); s2 += bf2f(pp[2]); s3 += bf2f(pp[3]);
        }
        const float* gp = gate + b * HIDN + c;
        v0 += gp[0] * s0; v1 += gp[1] * s1; v2 += gp[2] * s2; v3 += gp[3] * s3;
        float* op = outres + (size_t)r * HIDN + c;
        op[0] = v0; op[1] = v1; op[2] = v2; op[3] = v3;
      }
    }
    float ss = v0*v0 + v1*v1 + v2*v2 + v3*v3;
    #pragma unroll
    for (int off = 1; off < 64; off <<= 1) ss += __shfl_xor(ss, off);
    if ((t & 63) == 0) redl[t >> 6] = ss;
    __syncthreads();
    float tot = redl[0] + redl[1] + redl[2] + redl[3];
    __syncthreads();
    u16* dst = fragA + ((size_t)(c >> 3)) * MP * 8 + (size_t)r * 8 + (c & 7);
    ushort4 ov;
    if (live){
      float rstd = rsqrtf(tot * (1.0f / HIDN) + EPSV);
      const float* scp = sc + b * HIDN + c;
      const float* shp = sh + b * HIDN + c;
      ov.x = f2bf(v0 * rstd * (1.f + scp[0]) + shp[0]);
      ov.y = f2bf(v1 * rstd * (1.f + scp[1]) + shp[1]);
      ov.z = f2bf(v2 * rstd * (1.f + scp[2]) + shp[2]);
      ov.w = f2bf(v3 * rstd * (1.f + scp[3]) + shp[3]);
    } else {
      ov.x = ov.y = ov.z = ov.w = 0;
    }
    *(ushort4*)dst = ov;
  }
}

// ---------------- skinny GEMM core: M=512(pad), Ntile=64, K streamed ----------------
// A: fragA bf16 [k/8][512][8] in global. W: fp32 [K][wN] row-major, staged transposed->bf16 LDS.
static __device__ __forceinline__ void gemm_core(
    const u16* __restrict__ fa,
    const float* __restrict__ Wa, int cb0,
    const float* __restrict__ Wb, int cb1,
    int wN, int kc0, int nouter, u16* lds, f4 acc[4][4])
{
  const int tid = threadIdx.x;
  const int lane = tid & 63, wave = tid >> 6;
  const int l15 = lane & 15, g = lane >> 4;
  const int wrow = wave * 64;
  const int sn = tid & 63, skb = (tid >> 6) * 8;
  const float* wbase = (sn < 32) ? (Wa + cb0 + sn) : (Wb + cb1 + (sn - 32));
  for (int ko = 0; ko < nouter; ++ko){
    __syncthreads();
    {
      const float* wp = wbase + (size_t)(kc0 * 8 + ko * 64 + skb) * wN;
      float f[8];
      #pragma unroll
      for (int j = 0; j < 8; ++j) f[j] = wp[(size_t)j * wN];
      u32* dst = (u32*)(lds + sn * 88 + skb);
      dst[0] = pack2(f[0], f[1]); dst[1] = pack2(f[2], f[3]);
      dst[2] = pack2(f[4], f[5]); dst[3] = pack2(f[6], f[7]);
    }
    __syncthreads();
    #pragma unroll
    for (int kk = 0; kk < 2; ++kk){
      int kcg = kc0 + ko * 8 + kk * 4 + g;
      bh8 a[4], bb[4];
      const u16* ap = fa + ((size_t)kcg * MP + wrow + l15) * 8;
      #pragma unroll
      for (int mf = 0; mf < 4; ++mf) a[mf] = *(const bh8*)(ap + mf * 128);
      #pragma unroll
      for (int nf = 0; nf < 4; ++nf) bb[nf] = *(const bh8*)(lds + (nf * 16 + l15) * 88 + kk * 32 + g * 8);
      #pragma unroll
      for (int mf = 0; mf < 4; ++mf)
        #pragma unroll
        for (int nf = 0; nf < 4; ++nf)
          acc[mf][nf] = MFMA(a[mf], bb[nf], acc[mf][nf]);
    }
  }
}

// ---------------- QKV GEMM + RoPE epilogue ----------------
__global__ __launch_bounds__(512) void k_qkv(
    const u16* __restrict__ n1, const float* __restrict__ Wq,
    const float* __restrict__ Wk, const float* __restrict__ Wv,
    const float* __restrict__ ropec, const float* __restrict__ ropes,
    u16* __restrict__ qf, u16* __restrict__ ks, u16* __restrict__ vs)
{
  __shared__ u16 lds[64 * 88];
  int bx = blockIdx.x;
  const float* Wa; int cb0, cb1, wN, head = 0, d0 = 0, type;
  if (bx < 32){ type = 0; head = bx >> 2; d0 = (bx & 3) * 32; Wa = Wq; wN = NHEAD * HD; cb0 = head * HD + d0; cb1 = cb0 + 128; }
  else if (bx < 36){ type = 1; d0 = (bx - 32) * 32; Wa = Wk; wN = HD; cb0 = d0; cb1 = d0 + 128; }
  else { type = 2; d0 = (bx - 36) * 64; Wa = Wv; wN = HD; cb0 = d0; cb1 = cb0 + 32; }
  f4 acc[4][4];
  #pragma unroll
  for (int i = 0; i < 4; ++i)
    #pragma unroll
    for (int j = 0; j < 4; ++j) acc[i][j] = (f4){0.f, 0.f, 0.f, 0.f};
  gemm_core(n1, Wa, cb0, Wa, cb1, wN, 0, 16, lds, acc);
  int tid = threadIdx.x, lane = tid & 63, wave = tid >> 6, l15 = lane & 15, g = lane >> 4;
  int wrow = wave * 64;
  #pragma unroll
  for (int mf = 0; mf < 4; ++mf)
    #pragma unroll
    for (int r = 0; r < 4; ++r){
      int row = wrow + mf * 16 + 4 * g + r;
      if (row >= MR) continue;
      int b = row / AHOR, tt = row - b * AHOR;
      if (type == 2){
        #pragma unroll
        for (int nf = 0; nf < 4; ++nf){
          int d = d0 + nf * 16 + l15;
          vs[((size_t)(b * AHOR + tt)) * HD + d] = f2bf(acc[mf][nf][r]);
        }
      } else {
        #pragma unroll
        for (int nf = 0; nf < 2; ++nf){
          int dA = d0 + nf * 16 + l15; // 0..127 freq index
          float cz = ropec[(size_t)(b * AHOR + tt) * 128 + dA];
          float sz = ropes[(size_t)(b * AHOR + tt) * 128 + dA];
          float a = acc[mf][nf][r], bv = acc[mf][nf + 2][r];
          float oA = a * cz - bv * sz;
          float oB = bv * cz + a * sz;
          if (type == 0){
            oA *= QSCALE; oB *= QSCALE;
            int rowp = head * AHOR + tt;
            int dB = dA + 128;
            qf[((size_t)(b * 32 + (dA >> 3))) * MP * 8 + (size_t)rowp * 8 + (dA & 7)] = f2bf(oA);
            qf[((size_t)(b * 32 + (dB >> 3))) * MP * 8 + (size_t)rowp * 8 + (dB & 7)] = f2bf(oB);
          } else {
            size_t kb = ((size_t)(b * AHOR + tt)) * HD;
            ks[kb + dA] = f2bf(oA);
            ks[kb + dA + 128] = f2bf(oB);
          }
        }
      }
    }
}

// ---------------- attention: per (strip, batch) flash partial ----------------
__global__ __launch_bounds__(512) void k_attn(
    const u16* __restrict__ qf, const u16* __restrict__ ks, const u16* __restrict__ vs,
    const float* __restrict__ pk, const float* __restrict__ pv,
    const int* __restrict__ mask, int layer,
    u16* __restrict__ opart, float* __restrict__ mrow, float* __restrict__ lrow)
{
  __shared__ u16 kv[256 * 88];   // union: K tile [64][264] (16896) / V^T [256][88] (22528)
  __shared__ u16 plds[MP * 72];  // P tile [512][72]
  int s = blockIdx.x, b = blockIdx.y;
  int tid = threadIdx.x, lane = tid & 63, wave = tid >> 6, l15 = lane & 15, g = lane >> 4;
  int wrow = wave * 64;
  { // stage K tile (bf16)
    int key = tid >> 3, ds = (tid & 7) * 32;
    int kg = s * 64 + key;
    u32* dst = (u32*)(kv + key * 264 + ds);
    if (kg < PFXN){
      const float* src = pk + (((size_t)b * NLAY + layer) * PFXN + kg) * HD + ds;
      #pragma unroll
      for (int j = 0; j < 16; ++j) dst[j] = pack2(src[2*j], src[2*j+1]);
    } else if (kg < SEQN){
      const u16* src = ks + ((size_t)b * AHOR + (kg - PFXN)) * HD + ds;
      #pragma unroll
      for (int j = 0; j < 16; ++j) dst[j] = ((const u32*)src)[j];
    } else {
      #pragma unroll
      for (int j = 0; j < 16; ++j) dst[j] = 0;
    }
  }
  bool valid[4];
  #pragma unroll
  for (int nf = 0; nf < 4; ++nf){
    int kg = s * 64 + nf * 16 + l15;
    valid[nf] = (kg < PFXN) ? (mask[b * PFXN + kg] != 0) : (kg < SEQN);
  }
  __syncthreads();
  // S = (Q*scale) K^T
  f4 acc[4][4];
  #pragma unroll
  for (int i = 0; i < 4; ++i)
    #pragma unroll
    for (int j = 0; j < 4; ++j) acc[i][j] = (f4){0.f,0.f,0.f,0.f};
  const u16* qb = qf + (size_t)b * 32 * MP * 8;
  #pragma unroll
  for (int ko = 0; ko < 4; ++ko)
    #pragma unroll
    for (int kk = 0; kk < 2; ++kk){
      int kc = ko * 8 + kk * 4 + g;
      bh8 a[4], bb[4];
      const u16* ap = qb + ((size_t)kc * MP + wrow + l15) * 8;
      #pragma unroll
      for (int mf = 0; mf < 4; ++mf) a[mf] = *(const bh8*)(ap + mf * 128);
      #pragma unroll
      for (int nf = 0; nf < 4; ++nf) bb[nf] = *(const bh8*)(kv + (nf * 16 + l15) * 264 + ko * 64 + kk * 32 + g * 8);
      #pragma unroll
      for (int mf = 0; mf < 4; ++mf)
        #pragma unroll
        for (int nf = 0; nf < 4; ++nf) acc[mf][nf] = MFMA(a[mf], bb[nf], acc[mf][nf]);
    }
  #pragma unroll
  for (int nf = 0; nf < 4; ++nf) if (!valid[nf]){
    #pragma unroll
    for (int mf = 0; mf < 4; ++mf){
      acc[mf][nf][0] = NEGV; acc[mf][nf][1] = NEGV; acc[mf][nf][2] = NEGV; acc[mf][nf][3] = NEGV;
    }
  }
  // online softmax (per-strip)
  #pragma unroll
  for (int mf = 0; mf < 4; ++mf)
    #pragma unroll
    for (int r = 0; r < 4; ++r){
      float m0 = fmaxf(fmaxf(acc[mf][0][r], acc[mf][1][r]), fmaxf(acc[mf][2][r], acc[mf][3][r]));
      #pragma unroll
      for (int off = 1; off < 16; off <<= 1) m0 = fmaxf(m0, __shfl_xor(m0, off));
      int row = wrow + mf * 16 + 4 * g + r;
      float sum = 0.f;
      #pragma unroll
      for (int nf = 0; nf < 4; ++nf){
        float p = __expf(acc[mf][nf][r] - m0);
        sum += p;
        plds[row * 72 + nf * 16 + l15] = f2bf(p);
      }
      #pragma unroll
      for (int off = 1; off < 16; off <<= 1) sum += __shfl_xor(sum, off);
      if (l15 == 0){
        mrow[((size_t)b * NSTR + s) * MP + row] = m0;
        lrow[((size_t)b * NSTR + s) * MP + row] = sum;
      }
    }
  __syncthreads(); // all K reads done, P visible
  { // stage V^T
    int key = tid >> 3, ds = (tid & 7) * 32;
    int kg = s * 64 + key;
    if (kg < PFXN){
      const float* src = pv + (((size_t)b * NLAY + layer) * PFXN + kg) * HD + ds;
      #pragma unroll
      for (int j = 0; j < 32; ++j) kv[(ds + j) * 88 + key] = f2bf(src[j]);
    } else if (kg < SEQN){
      const u16* src = vs + ((size_t)b * AHOR + (kg - PFXN)) * HD + ds;
      #pragma unroll
      for (int j = 0; j < 32; ++j) kv[(ds + j) * 88 + key] = src[j];
    } else {
      #pragma unroll
      for (int j = 0; j < 32; ++j) kv[(ds + j) * 88 + key] = 0;
    }
  }
  __syncthreads();
  // O_part = P V
  #pragma unroll
  for (int dc = 0; dc < 4; ++dc){
    f4 oc[4][4];
    #pragma unroll
    for (int i = 0; i < 4; ++i)
      #pragma unroll
      for (int j = 0; j < 4; ++j) oc[i][j] = (f4){0.f,0.f,0.f,0.f};
    #pragma unroll
    for (int kk = 0; kk < 2; ++kk){
      bh8 a[4], bb[4];
      #pragma unroll
      for (int mf = 0; mf < 4; ++mf) a[mf] = *(const bh8*)(plds + (wrow + mf * 16 + l15) * 72 + kk * 32 + g * 8);
      #pragma unroll
      for (int nf = 0; nf < 4; ++nf) bb[nf] = *(const bh8*)(kv + (dc * 64 + nf * 16 + l15) * 88 + kk * 32 + g * 8);
      #pragma unroll
      for (int mf = 0; mf < 4; ++mf)
        #pragma unroll
        for (int nf = 0; nf < 4; ++nf) oc[mf][nf] = MFMA(a[mf], bb[nf], oc[mf][nf]);
    }
    #pragma unroll
    for (int mf = 0; mf < 4; ++mf)
      #pragma unroll
      for (int r = 0; r < 4; ++r){
        int row = wrow + mf * 16 + 4 * g + r;
        if (row < MR){
          #pragma unroll
          for (int nf = 0; nf < 4; ++nf){
            int d = dc * 64 + nf * 16 + l15;
            opart[(((size_t)b * NSTR + s) * MR + row) * HD + d] = f2bf(oc[mf][nf][r]);
          }
        }
      }
  }
}

// ---------------- combine strips -> attn_out fragA ----------------
__global__ void k_comb(const u16* __restrict__ opart, const float* __restrict__ mrow,
                       const float* __restrict__ lrow, u16* __restrict__ ao)
{
  int b = blockIdx.y;
  int d = threadIdx.x; // 256
  int r0 = blockIdx.x * 16;
  for (int i = 0; i < 16; ++i){
    int row = r0 + i;
    float M = -3.0e38f;
    for (int s2 = 0; s2 < NSTR; ++s2) M = fmaxf(M, mrow[((size_t)b * NSTR + s2) * MP + row]);
    float L = 0.f, o = 0.f;
    for (int s2 = 0; s2 < NSTR; ++s2){
      float w = __expf(mrow[((size_t)b * NSTR + s2) * MP + row] - M);
      L += w * lrow[((size_t)b * NSTR + s2) * MP + row];
      o += w * bf2f(opart[(((size_t)b * NSTR + s2) * MR + row) * HD + d]);
    }
    float val = o / L;
    int h = row / AHOR, tt = row - h * AHOR;
    int col = h * HD + d;
    int rg = b * AHOR + tt;
    ao[((size_t)(col >> 3)) * MP * 8 + (size_t)rg * 8 + (col & 7)] = f2bf(val);
  }
}

// ---------------- split-K GEMM -> bf16 partials (O-proj / MLP-down) ----------------
__global__ __launch_bounds__(512) void k_gemm_part(
    const u16* __restrict__ fa, const float* __restrict__ W, int wN,
    int kcPerSlice, u16* __restrict__ outp)
{
  __shared__ u16 lds[64 * 88];
  int n0 = blockIdx.x * 64;
  int ksl = blockIdx.y;
  f4 acc[4][4];
  #pragma unroll
  for (int i = 0; i < 4; ++i)
    #pragma unroll
    for (int j = 0; j < 4; ++j) acc[i][j] = (f4){0.f,0.f,0.f,0.f};
  gemm_core(fa, W, n0, W, n0 + 32, wN, ksl * kcPerSlice, kcPerSlice / 8, lds, acc);
  int tid = threadIdx.x, lane = tid & 63, wave = tid >> 6, l15 = lane & 15, g = lane >> 4;
  int wrow = wave * 64;
  #pragma unroll
  for (int mf = 0; mf < 4; ++mf)
    #pragma unroll
    for (int r = 0; r < 4; ++r){
      int row = wrow + mf * 16 + 4 * g + r;
      #pragma unroll
      for (int nf = 0; nf < 4; ++nf)
        outp[((size_t)ksl * MP + row) * 1024 + n0 + nf * 16 + l15] = f2bf(acc[mf][nf][r]);
    }
}

// ---------------- MLP up: gelu(n2@Wg) * (n2@Wu) -> fragA ----------------
__global__ __launch_bounds__(512) void k_mlpup(
    const u16* __restrict__ n2, const float* __restrict__ Wg, const float* __restrict__ Wu,
    u16* __restrict__ mlpf)
{
  __shared__ u16 lds[64 * 88];
  int n0 = blockIdx.x * 32;
  f4 acc[4][4];
  #pragma unroll
  for (int i = 0; i < 4; ++i)
    #pragma unroll
    for (int j = 0; j < 4; ++j) acc[i][j] = (f4){0.f,0.f,0.f,0.f};
  gemm_core(n2, Wg, n0, Wu, n0, DMLP, 0, 16, lds, acc);
  int tid = threadIdx.x, lane = tid & 63, wave = tid >> 6, l15 = lane & 15, g = lane >> 4;
  int wrow = wave * 64;
  #pragma unroll
  for (int mf = 0; mf < 4; ++mf)
    #pragma unroll
    for (int r = 0; r < 4; ++r){
      int row = wrow + mf * 16 + 4 * g + r;
      #pragma unroll
      for (int nf = 0; nf < 2; ++nf){
        int col = n0 + nf * 16 + l15;
        float gg = acc[mf][nf][r], uu = acc[mf][nf + 2][r];
        float act = geluf_(gg) * uu;
        mlpf[((size_t)(col >> 3)) * MP * 8 + (size_t)row * 8 + (col & 7)] = f2bf(act);
      }
    }
}

// ---------------- final: out = nf @ W_act_out + b ----------------
__global__ void k_out(const u16* __restrict__ nfr, const float* __restrict__ W,
                      const float* __restrict__ bias, float* __restrict__ out)
{
  int t = threadIdx.x;
  int row = blockIdx.x * 8 + (t >> 5);
  int c = t & 31;
  float acc = bias[c];
  for (int k = 0; k < HIDN; ++k)
    acc += bf2f(nfr[((size_t)(k >> 3)) * MP * 8 + (size_t)row * 8 + (k & 7)]) * W[k * ADIMN + c];
  out[row * ADIMN + c] = acc;
}

extern "C" void kernel_launch(void* const* d_in, const int* in_sizes, int n_in,
                              void* d_out, int out_size, void* d_ws, size_t ws_size,
                              hipStream_t stream)
{
  const float* pk  = (const float*)d_in[0];
  const float* pv  = (const float*)d_in[1];
  const int*   msk = (const int*)d_in[2];
  const float* xt  = (const float*)d_in[3];
  const float* ts  = (const float*)d_in[4];
  const float* Wq  = (const float*)d_in[5];
  const float* Wk  = (const float*)d_in[6];
  const float* Wv  = (const float*)d_in[7];
  const float* Wo  = (const float*)d_in[8];
  const float* Wg  = (const float*)d_in[9];
  const float* Wu  = (const float*)d_in[10];
  const float* Wd  = (const float*)d_in[11];
  const float* A1  = (const float*)d_in[12];
  const float* A2  = (const float*)d_in[13];
  const float* Af  = (const float*)d_in[14];
  const float* Wai = (const float*)d_in[15];
  const float* bai = (const float*)d_in[16];
  const float* Wao = (const float*)d_in[17];
  const float* bao = (const float*)d_in[18];
  const float* Wti = (const float*)d_in[19];
  const float* bti = (const float*)d_in[20];
  const float* Wto = (const float*)d_in[21];
  const float* bto = (const float*)d_in[22];

  char* w = (char*)d_ws;
  size_t off = 0;
  auto alloc = [&](size_t bytes) -> char* {
    char* p = w + off; off += (bytes + 255) & ~(size_t)255; return p;
  };
  float* temb  = (float*)alloc((size_t)BATCH * HIDN * 4);
  float* ttmp  = (float*)alloc((size_t)BATCH * HIDN * 4);
  float* cond  = (float*)alloc((size_t)BATCH * HIDN * 4);
  int*   offs  = (int*)alloc(BATCH * 4);
  float* ropec = (float*)alloc((size_t)BATCH * AHOR * 128 * 4);
  float* ropes = (float*)alloc((size_t)BATCH * AHOR * 128 * 4);
  float* ada   = (float*)alloc((size_t)37 * 3 * BATCH * HIDN * 4);
  float* h     = (float*)alloc((size_t)MR * HIDN * 4);
  float* h1    = (float*)alloc((size_t)MR * HIDN * 4);
  u16*   n1    = (u16*)alloc((size_t)128 * MP * 8 * 2);
  u16*   n2    = (u16*)alloc((size_t)128 * MP * 8 * 2);
  u16*   qf    = (u16*)alloc((size_t)BATCH * 32 * MP * 8 * 2);
  u16*   kss   = (u16*)alloc((size_t)BATCH * AHOR * HD * 2);
  u16*   vss   = (u16*)alloc((size_t)BATCH * AHOR * HD * 2);
  u16*   opart = (u16*)alloc((size_t)BATCH * NSTR * MR * HD * 2);
  float* mrow  = (float*)alloc((size_t)BATCH * NSTR * MP * 4);
  float* lrow  = (float*)alloc((size_t)BATCH * NSTR * MP * 4);
  u16*   ao    = (u16*)alloc((size_t)256 * MP * 8 * 2);
  u16*   opp   = (u16*)alloc((size_t)4 * MP * 1024 * 2);
  u16*   mlpf  = (u16*)alloc((size_t)512 * MP * 8 * 2);
  u16*   mdp   = (u16*)alloc((size_t)4 * MP * 1024 * 2);
  if (off > ws_size) return;

  hipMemsetAsync(qf, 0, (size_t)BATCH * 32 * MP * 8 * 2, stream);

  k_prep<<<1, 256, 0, stream>>>(msk, ts, temb, offs, ropec, ropes);
  k_tproj<<<32, 256, 0, stream>>>(temb, Wti, bti, ttmp);
  k_tproj<<<32, 256, 0, stream>>>(ttmp, Wto, bto, cond);
  k_ada<<<dim3(24, 37), 128, 0, stream>>>(cond, A1, A2, Af, ada);
  k_hin<<<MR, 256, 0, stream>>>(xt, Wai, bai, h);

  auto AP = [&](int y, int comp){ return ada + ((size_t)y * 3 + comp) * BATCH * HIDN; };

  k_resnorm<<<128, 256, 0, stream>>>(0, h, nullptr, nullptr, AP(0,0), AP(0,1), nullptr, n1);

  for (int l = 0; l < NLAY; ++l){
    k_qkv<<<40, 512, 0, stream>>>(n1, Wq + (size_t)l * HIDN * NHEAD * HD,
                                  Wk + (size_t)l * HIDN * HD, Wv + (size_t)l * HIDN * HD,
                                  ropec, ropes, qf, kss, vss);
    k_attn<<<dim3(NSTR, BATCH), 512, 0, stream>>>(qf, kss, vss, pk, pv, msk, l, opart, mrow, lrow);
    k_comb<<<dim3(25, BATCH), 256, 0, stream>>>(opart, mrow, lrow, ao);
    k_gemm_part<<<dim3(16, 4), 512, 0, stream>>>(ao, Wo + (size_t)l * 2048 * 1024, 1024, 64, opp);
    k_resnorm<<<128, 256, 0, stream>>>(1, h, opp, AP(l,2), AP(NLAY+l,0), AP(NLAY+l,1), h1, n2);
    k_mlpup<<<128, 512, 0, stream>>>(n2, Wg + (size_t)l * HIDN * DMLP, Wu + (size_t)l * HIDN * DMLP, mlpf);
    k_gemm_part<<<dim3(16, 4), 512, 0, stream>>>(mlpf, Wd + (size_t)l * DMLP * 1024, 1024, 128, mdp);
    const float* nsc = (l < NLAY - 1) ? AP(l + 1, 0) : AP(36, 0);
    const float* nsh = (l < NLAY - 1) ? AP(l + 1, 1) : AP(36, 1);
    k_resnorm<<<128, 256, 0, stream>>>(2, h1, mdp, AP(NLAY+l,2), nsc, nsh, h, n1);
  }
  k_out<<<50, 256, 0, stream>>>(n1, Wao, bao, (float*)d_out);
}

// Round 2
// 4050.927 us; speedup vs baseline: 1.1388x; 1.1388x over previous
//
#include <hip/hip_runtime.h>

typedef unsigned short u16;
typedef unsigned int   u32;
typedef __attribute__((ext_vector_type(8))) short bh8;
typedef __attribute__((ext_vector_type(4))) float f4;

constexpr int BATCH = 8, HIDN = 1024, NHEAD = 8, HD = 256, NLAY = 18, DMLP = 4096;
constexpr int AHOR = 50, ADIMN = 32, PFXN = 1037, SEQN = 1087, NSTR = 17, MR = 400, MP = 512;
constexpr float EPSV = 1e-6f, NEGV = -2.3819763e38f, QSCALE = 0.0625f;

static __device__ __forceinline__ u16 f2bf(float x){
  union{float f; u32 u;} v; v.f = x;
  u32 r = (v.u + 0x7FFFu + ((v.u >> 16) & 1u)) >> 16;
  return (u16)r;
}
static __device__ __forceinline__ float bf2f(u16 u){
  union{u32 u; float f;} v; v.u = ((u32)u) << 16; return v.f;
}
static __device__ __forceinline__ u32 pack2(float a, float b){
  return (u32)f2bf(a) | ((u32)f2bf(b) << 16);
}
static __device__ __forceinline__ f4 MFMA(bh8 a, bh8 b, f4 c){
  return __builtin_amdgcn_mfma_f32_16x16x32_bf16(a, b, c, 0, 0, 0);
}
static __device__ __forceinline__ float siluf_(float x){ return x / (1.f + __expf(-x)); }
static __device__ __forceinline__ float geluf_(float x){
  float y = 0.7978845608028654f * (x + 0.044715f * x * x * x);
  float e = __expf(2.f * y);
  return 0.5f * x * (2.f - 2.f / (e + 1.f));
}

// ---------------- prep: temb, offs, rope tables ----------------
__global__ void k_prep(const int* __restrict__ mask, const float* __restrict__ ts,
                       float* __restrict__ temb, int* __restrict__ offs,
                       float* __restrict__ ropec, float* __restrict__ ropes)
{
  int t = threadIdx.x;
  if (t < BATCH){
    int s = 0; const int* mp = mask + t * PFXN;
    for (int k = 0; k < PFXN; ++k) s += (mp[k] != 0);
    offs[t] = s;
  }
  for (int i = t; i < BATCH * 512; i += 256){
    int b = i >> 9, j = i & 511;
    float frac = (float)j * (1.0f / 511.0f);
    float period = 0.004f * __expf(frac * 6.907755278982137f); // ln(1000)
    float arg = (6.283185307179586f / period) * ts[b];
    float s, c; sincosf(arg, &s, &c);
    temb[b * HIDN + j] = s;
    temb[b * HIDN + 512 + j] = c;
  }
  __syncthreads();
  for (int i = t; i < BATCH * AHOR * 128; i += 256){
    int d = i & 127, bt = i >> 7, b = bt / AHOR, tt = bt % AHOR;
    float inv = __expf(-((float)d * (1.f / 128.f)) * 9.210340371976184f); // ln(10000)
    float arg = (float)(offs[b] + tt) * inv;
    float s, c; sincosf(arg, &s, &c);
    ropec[i] = c; ropes[i] = s;
  }
}

// ---------------- tiny M=8 GEMM (1024x1024) + silu ----------------
__global__ void k_tproj(const float* __restrict__ X, const float* __restrict__ W,
                        const float* __restrict__ bias, float* __restrict__ out)
{
  __shared__ float xs[BATCH * HIDN];
  __shared__ float red[BATCH][8][32];
  int t = threadIdx.x;
  for (int i = t; i < BATCH * HIDN; i += 256) xs[i] = X[i];
  __syncthreads();
  int c = t & 31, kp = t >> 5;
  int c0 = blockIdx.x * 32;
  float acc[BATCH];
  #pragma unroll
  for (int b = 0; b < BATCH; ++b) acc[b] = 0.f;
  for (int k = kp * 128; k < kp * 128 + 128; ++k){
    float w = W[(size_t)k * HIDN + c0 + c];
    #pragma unroll
    for (int b = 0; b < BATCH; ++b) acc[b] += xs[b * HIDN + k] * w;
  }
  #pragma unroll
  for (int b = 0; b < BATCH; ++b) red[b][kp][c] = acc[b];
  __syncthreads();
  int b2 = t >> 5, c2 = t & 31;
  float s = bias[c0 + c2];
  #pragma unroll
  for (int kp2 = 0; kp2 < 8; ++kp2) s += red[b2][kp2][c2];
  out[b2 * HIDN + c0 + c2] = siluf_(s);
}

// ---------------- ada: cond @ {A1|A2|Af} -> scale/shift/gate for all layers ----------------
__global__ void k_ada(const float* __restrict__ cond, const float* __restrict__ A1,
                      const float* __restrict__ A2, const float* __restrict__ Af,
                      float* __restrict__ out)
{
  __shared__ float cs[BATCH * HIDN];
  int t = threadIdx.x; // 128
  for (int i = t; i < BATCH * HIDN; i += 128) cs[i] = cond[i];
  __syncthreads();
  int y = blockIdx.y; // 0..36
  const float* A = (y < NLAY) ? (A1 + (size_t)y * HIDN * 3072)
                  : (y < 2 * NLAY) ? (A2 + (size_t)(y - NLAY) * HIDN * 3072) : Af;
  int n = blockIdx.x * 128 + t; // 0..3071
  float acc[BATCH];
  #pragma unroll
  for (int b = 0; b < BATCH; ++b) acc[b] = 0.f;
  const float* ap = A + n;
  #pragma unroll 4
  for (int k = 0; k < HIDN; ++k){
    float a = ap[(size_t)k * 3072];
    #pragma unroll
    for (int b = 0; b < BATCH; ++b) acc[b] += cs[b * HIDN + k] * a;
  }
  float* o = out + ((size_t)y * 3 + (n >> 10)) * BATCH * HIDN + (n & 1023);
  #pragma unroll
  for (int b = 0; b < BATCH; ++b) o[b * HIDN] = acc[b];
}

// ---------------- h0 = x_t @ W_act_in + b ----------------
__global__ void k_hin(const float* __restrict__ xt, const float* __restrict__ W,
                      const float* __restrict__ bias, float* __restrict__ h)
{
  int r = blockIdx.x; // 0..399
  int t = threadIdx.x; int c0 = t * 4;
  __shared__ float xs[ADIMN];
  if (t < ADIMN) xs[t] = xt[r * ADIMN + t];
  __syncthreads();
  float a0 = bias[c0], a1 = bias[c0+1], a2 = bias[c0+2], a3 = bias[c0+3];
  for (int k = 0; k < ADIMN; ++k){
    float x = xs[k];
    const float* wp = W + k * HIDN + c0;
    a0 += x * wp[0]; a1 += x * wp[1]; a2 += x * wp[2]; a3 += x * wp[3];
  }
  float* hp = h + (size_t)r * HIDN + c0;
  hp[0] = a0; hp[1] = a1; hp[2] = a2; hp[3] = a3;
}

// ---------------- residual + RMS + AdaNorm -> fragA bf16 ----------------
__global__ void k_resnorm(int mode, int np,
    const float* __restrict__ base, const u16* __restrict__ parts,
    const float* __restrict__ gate, const float* __restrict__ sc,
    const float* __restrict__ sh, float* __restrict__ outres,
    u16* __restrict__ fragA)
{
  __shared__ float redl[4];
  int t = threadIdx.x;
  int c = t * 4;
  for (int i = 0; i < 4; ++i){
    int r = blockIdx.x * 4 + i;
    bool live = (r < MR);
    float v0 = 0, v1 = 0, v2 = 0, v3 = 0;
    int b = live ? (r / AHOR) : 0;
    if (live){
      const float* bp = base + (size_t)r * HIDN + c;
      v0 = bp[0]; v1 = bp[1]; v2 = bp[2]; v3 = bp[3];
      if (mode){
        float s0 = 0, s1 = 0, s2 = 0, s3 = 0;
        for (int p = 0; p < np; ++p){
          const u16* pp = parts + ((size_t)p * MP + r) * HIDN + c;
          s0 += bf2f(pp[0]); s1 += bf2f(pp[1]); s2 += bf2f(pp[2]); s3 += bf2f(pp[3]);
        }
        const float* gp = gate + b * HIDN + c;
        v0 += gp[0] * s0; v1 += gp[1] * s1; v2 += gp[2] * s2; v3 += gp[3] * s3;
        float* op = outres + (size_t)r * HIDN + c;
        op[0] = v0; op[1] = v1; op[2] = v2; op[3] = v3;
      }
    }
    float ss = v0*v0 + v1*v1 + v2*v2 + v3*v3;
    #pragma unroll
    for (int off = 1; off < 64; off <<= 1) ss += __shfl_xor(ss, off);
    if ((t & 63) == 0) redl[t >> 6] = ss;
    __syncthreads();
    float tot = redl[0] + redl[1] + redl[2] + redl[3];
    __syncthreads();
    u16* dst = fragA + ((size_t)(c >> 3)) * MP * 8 + (size_t)r * 8 + (c & 7);
    ushort4 ov;
    if (live){
      float rstd = rsqrtf(tot * (1.0f / HIDN) + EPSV);
      const float* scp = sc + b * HIDN + c;
      const float* shp = sh + b * HIDN + c;
      ov.x = f2bf(v0 * rstd * (1.f + scp[0]) + shp[0]);
      ov.y = f2bf(v1 * rstd * (1.f + scp[1]) + shp[1]);
      ov.z = f2bf(v2 * rstd * (1.f + scp[2]) + shp[2]);
      ov.w = f2bf(v3 * rstd * (1.f + scp[3]) + shp[3]);
    } else {
      ov.x = ov.y = ov.z = ov.w = 0;
    }
    *(ushort4*)dst = ov;
  }
}

// ---------------- pipelined skinny GEMM core, 64-col tile ----------------
// A: fragA bf16 [kc][512][8] global. W: fp32 [K][wN] row-major; cols cb0..cb0+31 (Wa)
// and cb1..cb1+31 (Wb) staged transposed->bf16 LDS with 2-phase register prefetch.
template<int NOUTER>
static __device__ __forceinline__ void gemm_core64(
    const u16* __restrict__ fa,
    const float* __restrict__ Wa, int cb0,
    const float* __restrict__ Wb, int cb1,
    int wN, int kc0, u16* lds, f4 acc[4][4])
{
  const int tid = threadIdx.x;
  const int lane = tid & 63, wave = tid >> 6;
  const int l15 = lane & 15, g = lane >> 4;
  const int wrow = wave * 64;
  const int sn = tid & 63, skb = (tid >> 6) * 8;
  const float* wbase = (sn < 32) ? (Wa + cb0 + sn) : (Wb + cb1 + (sn - 32));
  float cur[8], nxt[8];
  {
    const float* wp = wbase + (size_t)(kc0 * 8 + skb) * wN;
    #pragma unroll
    for (int j = 0; j < 8; ++j) cur[j] = wp[(size_t)j * wN];
  }
  #pragma unroll
  for (int ko = 0; ko < NOUTER; ++ko){
    u32* dst = (u32*)(lds + sn * 88 + skb);
    dst[0] = pack2(cur[0], cur[1]); dst[1] = pack2(cur[2], cur[3]);
    dst[2] = pack2(cur[4], cur[5]); dst[3] = pack2(cur[6], cur[7]);
    __syncthreads();
    if (ko + 1 < NOUTER){
      const float* wp = wbase + (size_t)(kc0 * 8 + (ko + 1) * 64 + skb) * wN;
      #pragma unroll
      for (int j = 0; j < 8; ++j) nxt[j] = wp[(size_t)j * wN];
    }
    #pragma unroll
    for (int kk = 0; kk < 2; ++kk){
      int kcg = kc0 + ko * 8 + kk * 4 + g;
      bh8 a[4], bb[4];
      const u16* ap = fa + ((size_t)kcg * MP + wrow + l15) * 8;
      #pragma unroll
      for (int mf = 0; mf < 4; ++mf) a[mf] = *(const bh8*)(ap + mf * 128);
      #pragma unroll
      for (int nf = 0; nf < 4; ++nf) bb[nf] = *(const bh8*)(lds + (nf * 16 + l15) * 88 + kk * 32 + g * 8);
      #pragma unroll
      for (int mf = 0; mf < 4; ++mf)
        #pragma unroll
        for (int nf = 0; nf < 4; ++nf)
          acc[mf][nf] = MFMA(a[mf], bb[nf], acc[mf][nf]);
    }
    __syncthreads();
    if (ko + 1 < NOUTER){
      #pragma unroll
      for (int j = 0; j < 8; ++j) cur[j] = nxt[j];
    }
  }
}

// ---------------- pipelined skinny GEMM core, 16+16-col tile ----------------
template<int NOUTER>
static __device__ __forceinline__ void gemm_core32(
    const u16* __restrict__ fa,
    const float* __restrict__ Wa, int cb0,
    const float* __restrict__ Wb, int cb1,
    int wN, u16* lds, f4 acc[4][2])
{
  const int tid = threadIdx.x;
  const int lane = tid & 63, wave = tid >> 6;
  const int l15 = lane & 15, g = lane >> 4;
  const int wrow = wave * 64;
  const int sc = tid & 31, skb = (tid >> 5) * 4; // 16 k-groups of 4
  const float* wbase = (sc < 16) ? (Wa + cb0 + sc) : (Wb + cb1 + (sc - 16));
  float cur[4], nxt[4];
  {
    #pragma unroll
    for (int j = 0; j < 4; ++j) cur[j] = wbase[(size_t)(skb + j) * wN];
  }
  #pragma unroll
  for (int ko = 0; ko < NOUTER; ++ko){
    u32* dst = (u32*)(lds + sc * 72 + skb);
    dst[0] = pack2(cur[0], cur[1]); dst[1] = pack2(cur[2], cur[3]);
    __syncthreads();
    if (ko + 1 < NOUTER){
      const float* wp = wbase + (size_t)((ko + 1) * 64 + skb) * wN;
      #pragma unroll
      for (int j = 0; j < 4; ++j) nxt[j] = wp[(size_t)j * wN];
    }
    #pragma unroll
    for (int kk = 0; kk < 2; ++kk){
      int kcg = ko * 8 + kk * 4 + g;
      bh8 a[4], bb[2];
      const u16* ap = fa + ((size_t)kcg * MP + wrow + l15) * 8;
      #pragma unroll
      for (int mf = 0; mf < 4; ++mf) a[mf] = *(const bh8*)(ap + mf * 128);
      #pragma unroll
      for (int nf = 0; nf < 2; ++nf) bb[nf] = *(const bh8*)(lds + (nf * 16 + l15) * 72 + kk * 32 + g * 8);
      #pragma unroll
      for (int mf = 0; mf < 4; ++mf)
        #pragma unroll
        for (int nf = 0; nf < 2; ++nf)
          acc[mf][nf] = MFMA(a[mf], bb[nf], acc[mf][nf]);
    }
    __syncthreads();
    if (ko + 1 < NOUTER){
      #pragma unroll
      for (int j = 0; j < 4; ++j) cur[j] = nxt[j];
    }
  }
}

// ---------------- QKV partial GEMM (split-K x4) ----------------
__global__ __launch_bounds__(512) void k_qkv_part(
    const u16* __restrict__ n1, const float* __restrict__ Wq,
    const float* __restrict__ Wk, const float* __restrict__ Wv,
    u16* __restrict__ qkvp)
{
  __shared__ u16 lds[64 * 88];
  int bx = blockIdx.x, ksl = blockIdx.y;
  const float* W; int wN, cb0, colbase;
  if (bx < 32){ W = Wq; wN = NHEAD * HD; cb0 = bx * 64; colbase = bx * 64; }
  else if (bx < 36){ W = Wk; wN = HD; cb0 = (bx - 32) * 64; colbase = 2048 + cb0; }
  else { W = Wv; wN = HD; cb0 = (bx - 36) * 64; colbase = 2304 + cb0; }
  f4 acc[4][4];
  #pragma unroll
  for (int i = 0; i < 4; ++i)
    #pragma unroll
    for (int j = 0; j < 4; ++j) acc[i][j] = (f4){0.f, 0.f, 0.f, 0.f};
  gemm_core64<4>(n1, W, cb0, W, cb0 + 32, wN, ksl * 32, lds, acc);
  int tid = threadIdx.x, lane = tid & 63, wave = tid >> 6, l15 = lane & 15, g = lane >> 4;
  int wrow = wave * 64;
  #pragma unroll
  for (int mf = 0; mf < 4; ++mf)
    #pragma unroll
    for (int r = 0; r < 4; ++r){
      int row = wrow + mf * 16 + 4 * g + r;
      #pragma unroll
      for (int nf = 0; nf < 4; ++nf)
        qkvp[((size_t)ksl * MP + row) * 2560 + colbase + nf * 16 + l15] = f2bf(acc[mf][nf][r]);
    }
}

// ---------------- combine QKV partials + RoPE -> qf/ks/vs ----------------
__global__ void k_qkv_rope(const u16* __restrict__ qkvp,
                           const float* __restrict__ ropec, const float* __restrict__ ropes,
                           u16* __restrict__ qf, u16* __restrict__ ks, u16* __restrict__ vs)
{
  int r = blockIdx.x; // 0..399
  int b = r / AHOR, tt = r - b * AHOR;
  int t = threadIdx.x;
  const u16* base = qkvp + (size_t)r * 2560;
  const size_t SL = (size_t)MP * 2560;
  #pragma unroll
  for (int i = 0; i < 4; ++i){
    int idx = t + 256 * i; int head = idx >> 7, dA = idx & 127;
    int cL = head * 256 + dA, cH = cL + 128;
    float lo = bf2f(base[cL]) + bf2f(base[SL + cL]) + bf2f(base[2 * SL + cL]) + bf2f(base[3 * SL + cL]);
    float hi = bf2f(base[cH]) + bf2f(base[SL + cH]) + bf2f(base[2 * SL + cH]) + bf2f(base[3 * SL + cH]);
    float cz = ropec[(size_t)r * 128 + dA], sz = ropes[(size_t)r * 128 + dA];
    float oA = (lo * cz - hi * sz) * QSCALE;
    float oB = (hi * cz + lo * sz) * QSCALE;
    int rowp = head * AHOR + tt;
    int dB = dA + 128;
    qf[((size_t)(b * 32 + (dA >> 3))) * MP * 8 + (size_t)rowp * 8 + (dA & 7)] = f2bf(oA);
    qf[((size_t)(b * 32 + (dB >> 3))) * MP * 8 + (size_t)rowp * 8 + (dB & 7)] = f2bf(oB);
  }
  if (t < 128){
    int dA = t, cL = 2048 + dA, cH = cL + 128;
    float lo = bf2f(base[cL]) + bf2f(base[SL + cL]) + bf2f(base[2 * SL + cL]) + bf2f(base[3 * SL + cL]);
    float hi = bf2f(base[cH]) + bf2f(base[SL + cH]) + bf2f(base[2 * SL + cH]) + bf2f(base[3 * SL + cH]);
    float cz = ropec[(size_t)r * 128 + dA], sz = ropes[(size_t)r * 128 + dA];
    ks[(size_t)r * HD + dA] = f2bf(lo * cz - hi * sz);
    ks[(size_t)r * HD + dA + 128] = f2bf(hi * cz + lo * sz);
  }
  {
    int c = 2304 + t;
    float v = bf2f(base[c]) + bf2f(base[SL + c]) + bf2f(base[2 * SL + c]) + bf2f(base[3 * SL + c]);
    vs[(size_t)r * HD + t] = f2bf(v);
  }
}

// ---------------- attention: per (strip, batch) flash partial, V prefetched ----------------
__global__ __launch_bounds__(512) void k_attn(
    const u16* __restrict__ qf, const u16* __restrict__ ks, const u16* __restrict__ vs,
    const float* __restrict__ pk, const float* __restrict__ pv,
    const int* __restrict__ mask, int layer,
    u16* __restrict__ opart, float* __restrict__ mrow, float* __restrict__ lrow)
{
  __shared__ u16 kv[256 * 88];   // union: K tile [64][264] / V^T [256][88] skewed
  __shared__ u16 plds[MP * 72];  // P tile [512][72]
  int s = blockIdx.x, b = blockIdx.y;
  int tid = threadIdx.x, lane = tid & 63, wave = tid >> 6, l15 = lane & 15, g = lane >> 4;
  int wrow = wave * 64;
  int key = tid >> 3, dblk = (tid & 7) * 32;
  int kg = s * 64 + key;
  { // stage K tile (bf16) direct to LDS
    u32* dst = (u32*)(kv + key * 264 + dblk);
    if (kg < PFXN){
      const float4* src = (const float4*)(pk + (((size_t)b * NLAY + layer) * PFXN + kg) * HD + dblk);
      #pragma unroll
      for (int j = 0; j < 8; ++j){ float4 v = src[j]; dst[2*j] = pack2(v.x, v.y); dst[2*j+1] = pack2(v.z, v.w); }
    } else if (kg < SEQN){
      const u32* src = (const u32*)(ks + ((size_t)b * AHOR + (kg - PFXN)) * HD + dblk);
      #pragma unroll
      for (int j = 0; j < 16; ++j) dst[j] = src[j];
    } else {
      #pragma unroll
      for (int j = 0; j < 16; ++j) dst[j] = 0;
    }
  }
  // prefetch V tile into registers (latency hides under QK^T + softmax)
  float vreg[32];
  if (kg < PFXN){
    const float4* src = (const float4*)(pv + (((size_t)b * NLAY + layer) * PFXN + kg) * HD + dblk);
    #pragma unroll
    for (int j = 0; j < 8; ++j){ float4 v = src[j]; vreg[4*j] = v.x; vreg[4*j+1] = v.y; vreg[4*j+2] = v.z; vreg[4*j+3] = v.w; }
  } else if (kg < SEQN){
    const u32* src = (const u32*)(vs + ((size_t)b * AHOR + (kg - PFXN)) * HD + dblk);
    #pragma unroll
    for (int j = 0; j < 16; ++j){ u32 u = src[j]; vreg[2*j] = bf2f((u16)(u & 0xFFFF)); vreg[2*j+1] = bf2f((u16)(u >> 16)); }
  } else {
    #pragma unroll
    for (int j = 0; j < 32; ++j) vreg[j] = 0.f;
  }
  bool valid[4];
  #pragma unroll
  for (int nf = 0; nf < 4; ++nf){
    int kgc = s * 64 + nf * 16 + l15;
    valid[nf] = (kgc < PFXN) ? (mask[b * PFXN + kgc] != 0) : (kgc < SEQN);
  }
  __syncthreads();
  // S = (Q*scale) K^T
  f4 acc[4][4];
  #pragma unroll
  for (int i = 0; i < 4; ++i)
    #pragma unroll
    for (int j = 0; j < 4; ++j) acc[i][j] = (f4){0.f,0.f,0.f,0.f};
  const u16* qb = qf + (size_t)b * 32 * MP * 8;
  #pragma unroll
  for (int ko = 0; ko < 4; ++ko)
    #pragma unroll
    for (int kk = 0; kk < 2; ++kk){
      int kc = ko * 8 + kk * 4 + g;
      bh8 a[4], bb[4];
      const u16* ap = qb + ((size_t)kc * MP + wrow + l15) * 8;
      #pragma unroll
      for (int mf = 0; mf < 4; ++mf) a[mf] = *(const bh8*)(ap + mf * 128);
      #pragma unroll
      for (int nf = 0; nf < 4; ++nf) bb[nf] = *(const bh8*)(kv + (nf * 16 + l15) * 264 + ko * 64 + kk * 32 + g * 8);
      #pragma unroll
      for (int mf = 0; mf < 4; ++mf)
        #pragma unroll
        for (int nf = 0; nf < 4; ++nf) acc[mf][nf] = MFMA(a[mf], bb[nf], acc[mf][nf]);
    }
  #pragma unroll
  for (int nf = 0; nf < 4; ++nf) if (!valid[nf]){
    #pragma unroll
    for (int mf = 0; mf < 4; ++mf){
      acc[mf][nf][0] = NEGV; acc[mf][nf][1] = NEGV; acc[mf][nf][2] = NEGV; acc[mf][nf][3] = NEGV;
    }
  }
  // per-strip softmax
  #pragma unroll
  for (int mf = 0; mf < 4; ++mf)
    #pragma unroll
    for (int r = 0; r < 4; ++r){
      float m0 = fmaxf(fmaxf(acc[mf][0][r], acc[mf][1][r]), fmaxf(acc[mf][2][r], acc[mf][3][r]));
      #pragma unroll
      for (int off = 1; off < 16; off <<= 1) m0 = fmaxf(m0, __shfl_xor(m0, off));
      int row = wrow + mf * 16 + 4 * g + r;
      float sum = 0.f;
      #pragma unroll
      for (int nf = 0; nf < 4; ++nf){
        float p = __expf(acc[mf][nf][r] - m0);
        sum += p;
        plds[row * 72 + nf * 16 + l15] = f2bf(p);
      }
      #pragma unroll
      for (int off = 1; off < 16; off <<= 1) sum += __shfl_xor(sum, off);
      if (l15 == 0){
        mrow[((size_t)b * NSTR + s) * MP + row] = m0;
        lrow[((size_t)b * NSTR + s) * MP + row] = sum;
      }
    }
  __syncthreads(); // all K reads done, P visible
  { // write V^T from regs with skewed layout (bank-conflict reduction)
    #pragma unroll
    for (int j = 0; j < 32; ++j){
      int d = dblk + j;
      kv[d * 88 + ((d >> 5) & 3) * 8 + key] = f2bf(vreg[j]);
    }
  }
  __syncthreads();
  // O_part = P V
  #pragma unroll
  for (int dc = 0; dc < 4; ++dc){
    f4 oc[4][4];
    #pragma unroll
    for (int i = 0; i < 4; ++i)
      #pragma unroll
      for (int j = 0; j < 4; ++j) oc[i][j] = (f4){0.f,0.f,0.f,0.f};
    #pragma unroll
    for (int kk = 0; kk < 2; ++kk){
      bh8 a[4], bb[4];
      #pragma unroll
      for (int mf = 0; mf < 4; ++mf) a[mf] = *(const bh8*)(plds + (wrow + mf * 16 + l15) * 72 + kk * 32 + g * 8);
      #pragma unroll
      for (int nf = 0; nf < 4; ++nf){
        int dcol = dc * 64 + nf * 16 + l15;
        bb[nf] = *(const bh8*)(kv + dcol * 88 + ((dcol >> 5) & 3) * 8 + kk * 32 + g * 8);
      }
      #pragma unroll
      for (int mf = 0; mf < 4; ++mf)
        #pragma unroll
        for (int nf = 0; nf < 4; ++nf) oc[mf][nf] = MFMA(a[mf], bb[nf], oc[mf][nf]);
    }
    #pragma unroll
    for (int mf = 0; mf < 4; ++mf)
      #pragma unroll
      for (int r = 0; r < 4; ++r){
        int row = wrow + mf * 16 + 4 * g + r;
        if (row < MR){
          #pragma unroll
          for (int nf = 0; nf < 4; ++nf){
            int d = dc * 64 + nf * 16 + l15;
            opart[(((size_t)b * NSTR + s) * MR + row) * HD + d] = f2bf(oc[mf][nf][r]);
          }
        }
      }
  }
}

// ---------------- combine strips -> attn_out fragA ----------------
__global__ void k_comb(const u16* __restrict__ opart, const float* __restrict__ mrow,
                       const float* __restrict__ lrow, u16* __restrict__ ao)
{
  int b = blockIdx.y;
  int d = threadIdx.x; // 256
  int r0 = blockIdx.x * 16;
  for (int i = 0; i < 16; ++i){
    int row = r0 + i;
    float M = -3.0e38f;
    for (int s2 = 0; s2 < NSTR; ++s2) M = fmaxf(M, mrow[((size_t)b * NSTR + s2) * MP + row]);
    float L = 0.f, o = 0.f;
    for (int s2 = 0; s2 < NSTR; ++s2){
      float w = __expf(mrow[((size_t)b * NSTR + s2) * MP + row] - M);
      L += w * lrow[((size_t)b * NSTR + s2) * MP + row];
      o += w * bf2f(opart[(((size_t)b * NSTR + s2) * MR + row) * HD + d]);
    }
    float val = o / L;
    int h = row / AHOR, tt = row - h * AHOR;
    int col = h * HD + d;
    int rg = b * AHOR + tt;
    ao[((size_t)(col >> 3)) * MP * 8 + (size_t)rg * 8 + (col & 7)] = f2bf(val);
  }
}

// ---------------- split-K GEMM -> bf16 partials (O-proj / MLP-down) ----------------
template<int NOUTER>
__global__ __launch_bounds__(512) void k_gemm_part(
    const u16* __restrict__ fa, const float* __restrict__ W, int wN,
    int kcPerSlice, u16* __restrict__ outp)
{
  __shared__ u16 lds[64 * 88];
  int n0 = blockIdx.x * 64;
  int ksl = blockIdx.y;
  f4 acc[4][4];
  #pragma unroll
  for (int i = 0; i < 4; ++i)
    #pragma unroll
    for (int j = 0; j < 4; ++j) acc[i][j] = (f4){0.f,0.f,0.f,0.f};
  gemm_core64<NOUTER>(fa, W, n0, W, n0 + 32, wN, ksl * kcPerSlice, lds, acc);
  int tid = threadIdx.x, lane = tid & 63, wave = tid >> 6, l15 = lane & 15, g = lane >> 4;
  int wrow = wave * 64;
  #pragma unroll
  for (int mf = 0; mf < 4; ++mf)
    #pragma unroll
    for (int r = 0; r < 4; ++r){
      int row = wrow + mf * 16 + 4 * g + r;
      #pragma unroll
      for (int nf = 0; nf < 4; ++nf)
        outp[((size_t)ksl * MP + row) * 1024 + n0 + nf * 16 + l15] = f2bf(acc[mf][nf][r]);
    }
}

// ---------------- MLP up: gelu(n2@Wg) * (n2@Wu) -> fragA (Ntile 16, 256 blocks) ----------------
__global__ __launch_bounds__(512) void k_mlpup(
    const u16* __restrict__ n2, const float* __restrict__ Wg, const float* __restrict__ Wu,
    u16* __restrict__ mlpf)
{
  __shared__ u16 lds[32 * 72];
  int n0 = blockIdx.x * 16;
  f4 acc[4][2];
  #pragma unroll
  for (int i = 0; i < 4; ++i)
    #pragma unroll
    for (int j = 0; j < 2; ++j) acc[i][j] = (f4){0.f,0.f,0.f,0.f};
  gemm_core32<16>(n2, Wg, n0, Wu, n0, DMLP, lds, acc);
  int tid = threadIdx.x, lane = tid & 63, wave = tid >> 6, l15 = lane & 15, g = lane >> 4;
  int wrow = wave * 64;
  #pragma unroll
  for (int mf = 0; mf < 4; ++mf)
    #pragma unroll
    for (int r = 0; r < 4; ++r){
      int row = wrow + mf * 16 + 4 * g + r;
      int col = n0 + l15;
      float gg = acc[mf][0][r], uu = acc[mf][1][r];
      float act = geluf_(gg) * uu;
      mlpf[((size_t)(col >> 3)) * MP * 8 + (size_t)row * 8 + (col & 7)] = f2bf(act);
    }
}

// ---------------- final: out = nf @ W_act_out + b ----------------
__global__ void k_out(const u16* __restrict__ nfr, const float* __restrict__ W,
                      const float* __restrict__ bias, float* __restrict__ out)
{
  int t = threadIdx.x;
  int row = blockIdx.x * 8 + (t >> 5);
  int c = t & 31;
  float acc = bias[c];
  for (int k = 0; k < HIDN; ++k)
    acc += bf2f(nfr[((size_t)(k >> 3)) * MP * 8 + (size_t)row * 8 + (k & 7)]) * W[k * ADIMN + c];
  out[row * ADIMN + c] = acc;
}

extern "C" void kernel_launch(void* const* d_in, const int* in_sizes, int n_in,
                              void* d_out, int out_size, void* d_ws, size_t ws_size,
                              hipStream_t stream)
{
  const float* pk  = (const float*)d_in[0];
  const float* pv  = (const float*)d_in[1];
  const int*   msk = (const int*)d_in[2];
  const float* xt  = (const float*)d_in[3];
  const float* ts  = (const float*)d_in[4];
  const float* Wq  = (const float*)d_in[5];
  const float* Wk  = (const float*)d_in[6];
  const float* Wv  = (const float*)d_in[7];
  const float* Wo  = (const float*)d_in[8];
  const float* Wg  = (const float*)d_in[9];
  const float* Wu  = (const float*)d_in[10];
  const float* Wd  = (const float*)d_in[11];
  const float* A1  = (const float*)d_in[12];
  const float* A2  = (const float*)d_in[13];
  const float* Af  = (const float*)d_in[14];
  const float* Wai = (const float*)d_in[15];
  const float* bai = (const float*)d_in[16];
  const float* Wao = (const float*)d_in[17];
  const float* bao = (const float*)d_in[18];
  const float* Wti = (const float*)d_in[19];
  const float* bti = (const float*)d_in[20];
  const float* Wto = (const float*)d_in[21];
  const float* bto = (const float*)d_in[22];

  char* w = (char*)d_ws;
  size_t off = 0;
  auto alloc = [&](size_t bytes) -> char* {
    char* p = w + off; off += (bytes + 255) & ~(size_t)255; return p;
  };
  float* temb  = (float*)alloc((size_t)BATCH * HIDN * 4);
  float* ttmp  = (float*)alloc((size_t)BATCH * HIDN * 4);
  float* cond  = (float*)alloc((size_t)BATCH * HIDN * 4);
  int*   offs  = (int*)alloc(BATCH * 4);
  float* ropec = (float*)alloc((size_t)BATCH * AHOR * 128 * 4);
  float* ropes = (float*)alloc((size_t)BATCH * AHOR * 128 * 4);
  float* ada   = (float*)alloc((size_t)37 * 3 * BATCH * HIDN * 4);
  float* h     = (float*)alloc((size_t)MR * HIDN * 4);
  float* h1    = (float*)alloc((size_t)MR * HIDN * 4);
  u16*   n1    = (u16*)alloc((size_t)128 * MP * 8 * 2);
  u16*   n2    = (u16*)alloc((size_t)128 * MP * 8 * 2);
  u16*   qkvp  = (u16*)alloc((size_t)4 * MP * 2560 * 2);
  u16*   qf    = (u16*)alloc((size_t)BATCH * 32 * MP * 8 * 2);
  u16*   kss   = (u16*)alloc((size_t)BATCH * AHOR * HD * 2);
  u16*   vss   = (u16*)alloc((size_t)BATCH * AHOR * HD * 2);
  u16*   opart = (u16*)alloc((size_t)BATCH * NSTR * MR * HD * 2);
  float* mrow  = (float*)alloc((size_t)BATCH * NSTR * MP * 4);
  float* lrow  = (float*)alloc((size_t)BATCH * NSTR * MP * 4);
  u16*   ao    = (u16*)alloc((size_t)256 * MP * 8 * 2);
  u16*   opp   = (u16*)alloc((size_t)8 * MP * 1024 * 2);
  u16*   mlpf  = (u16*)alloc((size_t)512 * MP * 8 * 2);
  u16*   mdp   = (u16*)alloc((size_t)8 * MP * 1024 * 2);
  if (off > ws_size) return;

  k_prep<<<1, 256, 0, stream>>>(msk, ts, temb, offs, ropec, ropes);
  k_tproj<<<32, 256, 0, stream>>>(temb, Wti, bti, ttmp);
  k_tproj<<<32, 256, 0, stream>>>(ttmp, Wto, bto, cond);
  k_ada<<<dim3(24, 37), 128, 0, stream>>>(cond, A1, A2, Af, ada);
  k_hin<<<MR, 256, 0, stream>>>(xt, Wai, bai, h);

  auto AP = [&](int y, int comp){ return ada + ((size_t)y * 3 + comp) * BATCH * HIDN; };

  k_resnorm<<<128, 256, 0, stream>>>(0, 0, h, nullptr, nullptr, AP(0,0), AP(0,1), nullptr, n1);

  for (int l = 0; l < NLAY; ++l){
    k_qkv_part<<<dim3(40, 4), 512, 0, stream>>>(n1, Wq + (size_t)l * HIDN * NHEAD * HD,
                                                Wk + (size_t)l * HIDN * HD, Wv + (size_t)l * HIDN * HD, qkvp);
    k_qkv_rope<<<MR, 256, 0, stream>>>(qkvp, ropec, ropes, qf, kss, vss);
    k_attn<<<dim3(NSTR, BATCH), 512, 0, stream>>>(qf, kss, vss, pk, pv, msk, l, opart, mrow, lrow);
    k_comb<<<dim3(25, BATCH), 256, 0, stream>>>(opart, mrow, lrow, ao);
    k_gemm_part<4><<<dim3(16, 8), 512, 0, stream>>>(ao, Wo + (size_t)l * 2048 * 1024, 1024, 32, opp);
    k_resnorm<<<128, 256, 0, stream>>>(1, 8, h, opp, AP(l,2), AP(NLAY+l,0), AP(NLAY+l,1), h1, n2);
    k_mlpup<<<256, 512, 0, stream>>>(n2, Wg + (size_t)l * HIDN * DMLP, Wu + (size_t)l * HIDN * DMLP, mlpf);
    k_gemm_part<8><<<dim3(16, 8), 512, 0, stream>>>(mlpf, Wd + (size_t)l * DMLP * 1024, 1024, 64, mdp);
    const float* nsc = (l < NLAY - 1) ? AP(l + 1, 0) : AP(36, 0);
    const float* nsh = (l < NLAY - 1) ? AP(l + 1, 1) : AP(36, 1);
    k_resnorm<<<128, 256, 0, stream>>>(2, 8, h1, mdp, AP(NLAY+l,2), nsc, nsh, h, n1);
  }
  k_out<<<50, 256, 0, stream>>>(n1, Wao, bao, (float*)d_out);
}

// Round 3
// 3561.840 us; speedup vs baseline: 1.2952x; 1.1373x over previous
//
#include <hip/hip_runtime.h>

typedef unsigned short u16;
typedef unsigned int   u32;
typedef __attribute__((ext_vector_type(8))) short bh8;
typedef __attribute__((ext_vector_type(4))) float f4;

constexpr int BATCH = 8, HIDN = 1024, NHEAD = 8, HD = 256, NLAY = 18, DMLP = 4096;
constexpr int AHOR = 50, ADIMN = 32, PFXN = 1037, SEQN = 1087, NSTR = 17, MR = 400, MP = 512;
constexpr float EPSV = 1e-6f, NEGV = -2.3819763e38f, QSCALE = 0.0625f;

static __device__ __forceinline__ u16 f2bf(float x){
  union{float f; u32 u;} v; v.f = x;
  u32 r = (v.u + 0x7FFFu + ((v.u >> 16) & 1u)) >> 16;
  return (u16)r;
}
static __device__ __forceinline__ float bf2f(u16 u){
  union{u32 u; float f;} v; v.u = ((u32)u) << 16; return v.f;
}
static __device__ __forceinline__ u32 pack2(float a, float b){
  return (u32)f2bf(a) | ((u32)f2bf(b) << 16);
}
static __device__ __forceinline__ f4 MFMA(bh8 a, bh8 b, f4 c){
  return __builtin_amdgcn_mfma_f32_16x16x32_bf16(a, b, c, 0, 0, 0);
}
static __device__ __forceinline__ float siluf_(float x){ return x / (1.f + __expf(-x)); }
static __device__ __forceinline__ float geluf_(float x){
  float y = 0.7978845608028654f * (x + 0.044715f * x * x * x);
  float e = __expf(2.f * y);
  return 0.5f * x * (2.f - 2.f / (e + 1.f));
}

// ---------------- prep: temb, offs, rope tables ----------------
__global__ void k_prep(const int* __restrict__ mask, const float* __restrict__ ts,
                       float* __restrict__ temb, int* __restrict__ offs,
                       float* __restrict__ ropec, float* __restrict__ ropes)
{
  int t = threadIdx.x;
  { // parallel mask popcount: 32 lanes per batch
    int b = t >> 5, l = t & 31;
    const int* mp = mask + b * PFXN;
    int s = 0;
    for (int k = l; k < PFXN; k += 32) s += (mp[k] != 0);
    #pragma unroll
    for (int off = 16; off >= 1; off >>= 1) s += __shfl_xor(s, off);
    if (l == 0) offs[b] = s;
  }
  for (int i = t; i < BATCH * 512; i += 256){
    int b = i >> 9, j = i & 511;
    float frac = (float)j * (1.0f / 511.0f);
    float period = 0.004f * __expf(frac * 6.907755278982137f); // ln(1000)
    float arg = (6.283185307179586f / period) * ts[b];
    float s, c; sincosf(arg, &s, &c);
    temb[b * HIDN + j] = s;
    temb[b * HIDN + 512 + j] = c;
  }
  __syncthreads();
  for (int i = t; i < BATCH * AHOR * 128; i += 256){
    int d = i & 127, bt = i >> 7, b = bt / AHOR, tt = bt % AHOR;
    float inv = __expf(-((float)d * (1.f / 128.f)) * 9.210340371976184f); // ln(10000)
    float arg = (float)(offs[b] + tt) * inv;
    float s, c; sincosf(arg, &s, &c);
    ropec[i] = c; ropes[i] = s;
  }
}

// ---------------- tiny M=8 GEMM (1024x1024) + silu ----------------
__global__ void k_tproj(const float* __restrict__ X, const float* __restrict__ W,
                        const float* __restrict__ bias, float* __restrict__ out)
{
  __shared__ float xs[BATCH * HIDN];
  __shared__ float red[BATCH][8][32];
  int t = threadIdx.x;
  for (int i = t; i < BATCH * HIDN; i += 256) xs[i] = X[i];
  __syncthreads();
  int c = t & 31, kp = t >> 5;
  int c0 = blockIdx.x * 32;
  float acc[BATCH];
  #pragma unroll
  for (int b = 0; b < BATCH; ++b) acc[b] = 0.f;
  for (int k = kp * 128; k < kp * 128 + 128; ++k){
    float w = W[(size_t)k * HIDN + c0 + c];
    #pragma unroll
    for (int b = 0; b < BATCH; ++b) acc[b] += xs[b * HIDN + k] * w;
  }
  #pragma unroll
  for (int b = 0; b < BATCH; ++b) red[b][kp][c] = acc[b];
  __syncthreads();
  int b2 = t >> 5, c2 = t & 31;
  float s = bias[c0 + c2];
  #pragma unroll
  for (int kp2 = 0; kp2 < 8; ++kp2) s += red[b2][kp2][c2];
  out[b2 * HIDN + c0 + c2] = siluf_(s);
}

// ---------------- ada: cond @ {A1|A2|Af} -> scale/shift/gate for all layers ----------------
__global__ void k_ada(const float* __restrict__ cond, const float* __restrict__ A1,
                      const float* __restrict__ A2, const float* __restrict__ Af,
                      float* __restrict__ out)
{
  __shared__ float cs[BATCH * HIDN];
  int t = threadIdx.x; // 256
  for (int i = t; i < BATCH * HIDN; i += 256) cs[i] = cond[i];
  __syncthreads();
  int y = blockIdx.y; // 0..36
  const float* A = (y < NLAY) ? (A1 + (size_t)y * HIDN * 3072)
                  : (y < 2 * NLAY) ? (A2 + (size_t)(y - NLAY) * HIDN * 3072) : Af;
  int n = (blockIdx.x * 256 + t) * 4; // 0..3068
  f4 acc[BATCH];
  #pragma unroll
  for (int b = 0; b < BATCH; ++b) acc[b] = (f4){0.f,0.f,0.f,0.f};
  const float* ap = A + n;
  #pragma unroll 8
  for (int k = 0; k < HIDN; ++k){
    f4 a = *(const f4*)(ap + (size_t)k * 3072);
    #pragma unroll
    for (int b = 0; b < BATCH; ++b){
      float c = cs[b * HIDN + k];
      acc[b] += a * c;
    }
  }
  int comp = n >> 10, nn = n & 1023;
  float* o = out + ((size_t)y * 3 + comp) * BATCH * HIDN + nn;
  #pragma unroll
  for (int b = 0; b < BATCH; ++b) *(f4*)(o + b * HIDN) = acc[b];
}

// ---------------- h0 = x_t @ W_act_in + b ----------------
__global__ void k_hin(const float* __restrict__ xt, const float* __restrict__ W,
                      const float* __restrict__ bias, float* __restrict__ h)
{
  int r = blockIdx.x; // 0..399
  int t = threadIdx.x; int c0 = t * 4;
  __shared__ float xs[ADIMN];
  if (t < ADIMN) xs[t] = xt[r * ADIMN + t];
  __syncthreads();
  float a0 = bias[c0], a1 = bias[c0+1], a2 = bias[c0+2], a3 = bias[c0+3];
  for (int k = 0; k < ADIMN; ++k){
    float x = xs[k];
    const float* wp = W + k * HIDN + c0;
    a0 += x * wp[0]; a1 += x * wp[1]; a2 += x * wp[2]; a3 += x * wp[3];
  }
  float* hp = h + (size_t)r * HIDN + c0;
  hp[0] = a0; hp[1] = a1; hp[2] = a2; hp[3] = a3;
}

// ---------------- residual + RMS + AdaNorm -> fragA bf16 ----------------
__global__ void k_resnorm(int mode, int np,
    const float* __restrict__ base, const u16* __restrict__ parts,
    const float* __restrict__ gate, const float* __restrict__ sc,
    const float* __restrict__ sh, float* __restrict__ outres,
    u16* __restrict__ fragA)
{
  __shared__ float redl[4];
  int t = threadIdx.x;
  int c = t * 4;
  for (int i = 0; i < 4; ++i){
    int r = blockIdx.x * 4 + i;
    bool live = (r < MR);
    float4 v = {0.f,0.f,0.f,0.f};
    int b = live ? (r / AHOR) : 0;
    if (live){
      v = *(const float4*)(base + (size_t)r * HIDN + c);
      if (mode){
        float s0 = 0, s1 = 0, s2 = 0, s3 = 0;
        #pragma unroll 4
        for (int p = 0; p < np; ++p){
          ushort4 u4 = *(const ushort4*)(parts + ((size_t)p * MP + r) * HIDN + c);
          s0 += bf2f(u4.x); s1 += bf2f(u4.y); s2 += bf2f(u4.z); s3 += bf2f(u4.w);
        }
        float4 gp = *(const float4*)(gate + b * HIDN + c);
        v.x += gp.x * s0; v.y += gp.y * s1; v.z += gp.z * s2; v.w += gp.w * s3;
        *(float4*)(outres + (size_t)r * HIDN + c) = v;
      }
    }
    float ss = v.x*v.x + v.y*v.y + v.z*v.z + v.w*v.w;
    #pragma unroll
    for (int off = 1; off < 64; off <<= 1) ss += __shfl_xor(ss, off);
    if ((t & 63) == 0) redl[t >> 6] = ss;
    __syncthreads();
    float tot = redl[0] + redl[1] + redl[2] + redl[3];
    __syncthreads();
    u16* dst = fragA + ((size_t)(c >> 3)) * MP * 8 + (size_t)r * 8 + (c & 7);
    ushort4 ov;
    if (live){
      float rstd = rsqrtf(tot * (1.0f / HIDN) + EPSV);
      const float4 scp = *(const float4*)(sc + b * HIDN + c);
      const float4 shp = *(const float4*)(sh + b * HIDN + c);
      ov.x = f2bf(v.x * rstd * (1.f + scp.x) + shp.x);
      ov.y = f2bf(v.y * rstd * (1.f + scp.y) + shp.y);
      ov.z = f2bf(v.z * rstd * (1.f + scp.z) + shp.z);
      ov.w = f2bf(v.w * rstd * (1.f + scp.w) + shp.w);
    } else {
      ov.x = ov.y = ov.z = ov.w = 0;
    }
    *(ushort4*)dst = ov;
  }
}

// ---------------- GEMM core 64-col: double-buffered LDS, depth-2 W prefetch ----------------
// A: fragA bf16 [kc][512][8] global. W cols cb0..+31 (Wa) and cb1..+31 (Wb) -> bf16 LDS.
// One barrier per 64-k iteration. A-loads issued BEFORE W-prefetch so MFMA's vmcnt
// wait does not drain the prefetch.
template<int NOUTER>
static __device__ __forceinline__ void gemm_core64(
    const u16* __restrict__ fa,
    const float* __restrict__ Wa, int cb0,
    const float* __restrict__ Wb, int cb1,
    int wN, int kc0, u16* lds, f4 acc[4][4])
{
  const int tid = threadIdx.x;
  const int lane = tid & 63, wave = tid >> 6;
  const int l15 = lane & 15, g = lane >> 4;
  const int wrow = wave * 64;
  const int sn = tid & 63, skb = (tid >> 6) * 8;
  const float* wbase = (sn < 32) ? (Wa + cb0 + sn) : (Wb + cb1 + (sn - 32));
  const size_t krow0 = (size_t)kc0 * 8 + skb;
  float pre[2][8];
  #pragma unroll
  for (int j = 0; j < 8; ++j) pre[0][j] = wbase[(krow0 + j) * wN];
  if (NOUTER > 1){
    #pragma unroll
    for (int j = 0; j < 8; ++j) pre[1][j] = wbase[(krow0 + 64 + j) * wN];
  }
  { u32* dst = (u32*)(lds + sn * 88 + skb);
    dst[0] = pack2(pre[0][0], pre[0][1]); dst[1] = pack2(pre[0][2], pre[0][3]);
    dst[2] = pack2(pre[0][4], pre[0][5]); dst[3] = pack2(pre[0][6], pre[0][7]); }
  __syncthreads();
  #pragma unroll
  for (int ko = 0; ko < NOUTER; ++ko){
    u16* ldsr = lds + (ko & 1) * (64 * 88);
    // A fragments for both k-subgroups, issued first
    bh8 a[2][4];
    #pragma unroll
    for (int kk = 0; kk < 2; ++kk){
      int kcg = kc0 + ko * 8 + kk * 4 + g;
      const u16* ap = fa + ((size_t)kcg * MP + wrow + l15) * 8;
      #pragma unroll
      for (int mf = 0; mf < 4; ++mf) a[kk][mf] = *(const bh8*)(ap + mf * 128);
    }
    // W prefetch for ko+2 (stays in flight across MFMA + barrier)
    if (ko + 2 < NOUTER){
      #pragma unroll
      for (int j = 0; j < 8; ++j) pre[ko & 1][j] = wbase[(krow0 + (size_t)(ko + 2) * 64 + j) * wN];
    }
    #pragma unroll
    for (int kk = 0; kk < 2; ++kk){
      bh8 bb[4];
      #pragma unroll
      for (int nf = 0; nf < 4; ++nf) bb[nf] = *(const bh8*)(ldsr + (nf * 16 + l15) * 88 + kk * 32 + g * 8);
      #pragma unroll
      for (int mf = 0; mf < 4; ++mf)
        #pragma unroll
        for (int nf = 0; nf < 4; ++nf)
          acc[mf][nf] = MFMA(a[kk][mf], bb[nf], acc[mf][nf]);
    }
    if (ko + 1 < NOUTER){
      u16* ldsw = lds + ((ko + 1) & 1) * (64 * 88);
      u32* dst = (u32*)(ldsw + sn * 88 + skb);
      const float* p = pre[(ko + 1) & 1];
      dst[0] = pack2(p[0], p[1]); dst[1] = pack2(p[2], p[3]);
      dst[2] = pack2(p[4], p[5]); dst[3] = pack2(p[6], p[7]);
      __syncthreads();
    }
  }
}

// ---------------- GEMM core 32-col wide-K: 128 k/iter, double-buffered ----------------
template<int NOUTER> // NOUTER*128 = K
static __device__ __forceinline__ void gemm_core32w(
    const u16* __restrict__ fa,
    const float* __restrict__ Wa, int cb0,
    const float* __restrict__ Wb, int cb1,
    int wN, u16* lds, f4 acc[4][2])
{
  const int tid = threadIdx.x;
  const int lane = tid & 63, wave = tid >> 6;
  const int l15 = lane & 15, g = lane >> 4;
  const int wrow = wave * 64;
  const int sc = tid & 31, kq = tid >> 5; // 0..15
  const int kb = kq * 8;
  const float* wbase = (sc < 16) ? (Wa + cb0 + sc) : (Wb + cb1 + (sc - 16));
  float pre[2][8];
  #pragma unroll
  for (int j = 0; j < 8; ++j) pre[0][j] = wbase[(size_t)(kb + j) * wN];
  if (NOUTER > 1){
    #pragma unroll
    for (int j = 0; j < 8; ++j) pre[1][j] = wbase[(size_t)(128 + kb + j) * wN];
  }
  { u32* dst = (u32*)(lds + sc * 136 + kb);
    dst[0] = pack2(pre[0][0], pre[0][1]); dst[1] = pack2(pre[0][2], pre[0][3]);
    dst[2] = pack2(pre[0][4], pre[0][5]); dst[3] = pack2(pre[0][6], pre[0][7]); }
  __syncthreads();
  #pragma unroll
  for (int ko = 0; ko < NOUTER; ++ko){
    u16* ldsr = lds + (ko & 1) * (32 * 136);
    bh8 a[2][4];
    #pragma unroll
    for (int kk = 0; kk < 2; ++kk){
      int kcg = ko * 16 + kk * 4 + g;
      const u16* ap = fa + ((size_t)kcg * MP + wrow + l15) * 8;
      #pragma unroll
      for (int mf = 0; mf < 4; ++mf) a[kk][mf] = *(const bh8*)(ap + mf * 128);
    }
    if (ko + 2 < NOUTER){
      #pragma unroll
      for (int j = 0; j < 8; ++j) pre[ko & 1][j] = wbase[(size_t)((ko + 2) * 128 + kb + j) * wN];
    }
    #pragma unroll
    for (int kk = 0; kk < 2; ++kk){
      bh8 bb[2];
      #pragma unroll
      for (int nf = 0; nf < 2; ++nf) bb[nf] = *(const bh8*)(ldsr + (nf * 16 + l15) * 136 + kk * 32 + g * 8);
      #pragma unroll
      for (int mf = 0; mf < 4; ++mf){
        acc[mf][0] = MFMA(a[kk][mf], bb[0], acc[mf][0]);
        acc[mf][1] = MFMA(a[kk][mf], bb[1], acc[mf][1]);
      }
    }
    #pragma unroll
    for (int kk = 2; kk < 4; ++kk){
      int kcg = ko * 16 + kk * 4 + g;
      const u16* ap = fa + ((size_t)kcg * MP + wrow + l15) * 8;
      #pragma unroll
      for (int mf = 0; mf < 4; ++mf) a[kk - 2][mf] = *(const bh8*)(ap + mf * 128);
    }
    #pragma unroll
    for (int kk = 2; kk < 4; ++kk){
      bh8 bb[2];
      #pragma unroll
      for (int nf = 0; nf < 2; ++nf) bb[nf] = *(const bh8*)(ldsr + (nf * 16 + l15) * 136 + kk * 32 + g * 8);
      #pragma unroll
      for (int mf = 0; mf < 4; ++mf){
        acc[mf][0] = MFMA(a[kk - 2][mf], bb[0], acc[mf][0]);
        acc[mf][1] = MFMA(a[kk - 2][mf], bb[1], acc[mf][1]);
      }
    }
    if (ko + 1 < NOUTER){
      u16* ldsw = lds + ((ko + 1) & 1) * (32 * 136);
      u32* dst = (u32*)(ldsw + sc * 136 + kb);
      const float* p = pre[(ko + 1) & 1];
      dst[0] = pack2(p[0], p[1]); dst[1] = pack2(p[2], p[3]);
      dst[2] = pack2(p[4], p[5]); dst[3] = pack2(p[6], p[7]);
      __syncthreads();
    }
  }
}

// ---------------- QKV partial GEMM (split-K x4) ----------------
__global__ __launch_bounds__(512) void k_qkv_part(
    const u16* __restrict__ n1, const float* __restrict__ Wq,
    const float* __restrict__ Wk, const float* __restrict__ Wv,
    u16* __restrict__ qkvp)
{
  __shared__ u16 lds[2 * 64 * 88];
  int bx = blockIdx.x, ksl = blockIdx.y;
  const float* W; int wN, cb0, colbase;
  if (bx < 32){ W = Wq; wN = NHEAD * HD; cb0 = bx * 64; colbase = bx * 64; }
  else if (bx < 36){ W = Wk; wN = HD; cb0 = (bx - 32) * 64; colbase = 2048 + cb0; }
  else { W = Wv; wN = HD; cb0 = (bx - 36) * 64; colbase = 2304 + cb0; }
  f4 acc[4][4];
  #pragma unroll
  for (int i = 0; i < 4; ++i)
    #pragma unroll
    for (int j = 0; j < 4; ++j) acc[i][j] = (f4){0.f, 0.f, 0.f, 0.f};
  gemm_core64<4>(n1, W, cb0, W, cb0 + 32, wN, ksl * 32, lds, acc);
  int tid = threadIdx.x, lane = tid & 63, wave = tid >> 6, l15 = lane & 15, g = lane >> 4;
  int wrow = wave * 64;
  #pragma unroll
  for (int mf = 0; mf < 4; ++mf)
    #pragma unroll
    for (int r = 0; r < 4; ++r){
      int row = wrow + mf * 16 + 4 * g + r;
      #pragma unroll
      for (int nf = 0; nf < 4; ++nf)
        qkvp[((size_t)ksl * MP + row) * 2560 + colbase + nf * 16 + l15] = f2bf(acc[mf][nf][r]);
    }
}

// ---------------- combine QKV partials + RoPE -> qf/ks/vs ----------------
__global__ void k_qkv_rope(const u16* __restrict__ qkvp,
                           const float* __restrict__ ropec, const float* __restrict__ ropes,
                           u16* __restrict__ qf, u16* __restrict__ ks, u16* __restrict__ vs)
{
  int r = blockIdx.x; // 0..399
  int b = r / AHOR, tt = r - b * AHOR;
  int t = threadIdx.x;
  const u16* base = qkvp + (size_t)r * 2560;
  const size_t SL = (size_t)MP * 2560;
  #pragma unroll
  for (int i = 0; i < 4; ++i){
    int idx = t + 256 * i; int head = idx >> 7, dA = idx & 127;
    int cL = head * 256 + dA, cH = cL + 128;
    float lo = bf2f(base[cL]) + bf2f(base[SL + cL]) + bf2f(base[2 * SL + cL]) + bf2f(base[3 * SL + cL]);
    float hi = bf2f(base[cH]) + bf2f(base[SL + cH]) + bf2f(base[2 * SL + cH]) + bf2f(base[3 * SL + cH]);
    float cz = ropec[(size_t)r * 128 + dA], sz = ropes[(size_t)r * 128 + dA];
    float oA = (lo * cz - hi * sz) * QSCALE;
    float oB = (hi * cz + lo * sz) * QSCALE;
    int rowp = head * AHOR + tt;
    int dB = dA + 128;
    qf[((size_t)(b * 32 + (dA >> 3))) * MP * 8 + (size_t)rowp * 8 + (dA & 7)] = f2bf(oA);
    qf[((size_t)(b * 32 + (dB >> 3))) * MP * 8 + (size_t)rowp * 8 + (dB & 7)] = f2bf(oB);
  }
  if (t < 128){
    int dA = t, cL = 2048 + dA, cH = cL + 128;
    float lo = bf2f(base[cL]) + bf2f(base[SL + cL]) + bf2f(base[2 * SL + cL]) + bf2f(base[3 * SL + cL]);
    float hi = bf2f(base[cH]) + bf2f(base[SL + cH]) + bf2f(base[2 * SL + cH]) + bf2f(base[3 * SL + cH]);
    float cz = ropec[(size_t)r * 128 + dA], sz = ropes[(size_t)r * 128 + dA];
    ks[(size_t)r * HD + dA] = f2bf(lo * cz - hi * sz);
    ks[(size_t)r * HD + dA + 128] = f2bf(hi * cz + lo * sz);
  }
  {
    int c = 2304 + t;
    float v = bf2f(base[c]) + bf2f(base[SL + c]) + bf2f(base[2 * SL + c]) + bf2f(base[3 * SL + c]);
    vs[(size_t)r * HD + t] = f2bf(v);
  }
}

// ---------------- attention: per (strip, batch) flash partial, V prefetched ----------------
__global__ __launch_bounds__(512) void k_attn(
    const u16* __restrict__ qf, const u16* __restrict__ ks, const u16* __restrict__ vs,
    const float* __restrict__ pk, const float* __restrict__ pv,
    const int* __restrict__ mask, int layer,
    u16* __restrict__ opart, float* __restrict__ mrow, float* __restrict__ lrow)
{
  __shared__ u16 kv[256 * 88];   // union: K tile [64][264] / V^T [256][88] skewed
  __shared__ u16 plds[MP * 72];  // P tile [512][72]
  int s = blockIdx.x, b = blockIdx.y;
  int tid = threadIdx.x, lane = tid & 63, wave = tid >> 6, l15 = lane & 15, g = lane >> 4;
  int wrow = wave * 64;
  int key = tid >> 3, dblk = (tid & 7) * 32;
  int kg = s * 64 + key;
  { // stage K tile (bf16) direct to LDS
    u32* dst = (u32*)(kv + key * 264 + dblk);
    if (kg < PFXN){
      const float4* src = (const float4*)(pk + (((size_t)b * NLAY + layer) * PFXN + kg) * HD + dblk);
      #pragma unroll
      for (int j = 0; j < 8; ++j){ float4 v = src[j]; dst[2*j] = pack2(v.x, v.y); dst[2*j+1] = pack2(v.z, v.w); }
    } else if (kg < SEQN){
      const u32* src = (const u32*)(ks + ((size_t)b * AHOR + (kg - PFXN)) * HD + dblk);
      #pragma unroll
      for (int j = 0; j < 16; ++j) dst[j] = src[j];
    } else {
      #pragma unroll
      for (int j = 0; j < 16; ++j) dst[j] = 0;
    }
  }
  // prefetch V tile into registers (latency hides under QK^T + softmax)
  float vreg[32];
  if (kg < PFXN){
    const float4* src = (const float4*)(pv + (((size_t)b * NLAY + layer) * PFXN + kg) * HD + dblk);
    #pragma unroll
    for (int j = 0; j < 8; ++j){ float4 v = src[j]; vreg[4*j] = v.x; vreg[4*j+1] = v.y; vreg[4*j+2] = v.z; vreg[4*j+3] = v.w; }
  } else if (kg < SEQN){
    const u32* src = (const u32*)(vs + ((size_t)b * AHOR + (kg - PFXN)) * HD + dblk);
    #pragma unroll
    for (int j = 0; j < 16; ++j){ u32 u = src[j]; vreg[2*j] = bf2f((u16)(u & 0xFFFF)); vreg[2*j+1] = bf2f((u16)(u >> 16)); }
  } else {
    #pragma unroll
    for (int j = 0; j < 32; ++j) vreg[j] = 0.f;
  }
  bool valid[4];
  #pragma unroll
  for (int nf = 0; nf < 4; ++nf){
    int kgc = s * 64 + nf * 16 + l15;
    valid[nf] = (kgc < PFXN) ? (mask[b * PFXN + kgc] != 0) : (kgc < SEQN);
  }
  __syncthreads();
  // S = (Q*scale) K^T
  f4 acc[4][4];
  #pragma unroll
  for (int i = 0; i < 4; ++i)
    #pragma unroll
    for (int j = 0; j < 4; ++j) acc[i][j] = (f4){0.f,0.f,0.f,0.f};
  const u16* qb = qf + (size_t)b * 32 * MP * 8;
  #pragma unroll
  for (int ko = 0; ko < 4; ++ko)
    #pragma unroll
    for (int kk = 0; kk < 2; ++kk){
      int kc = ko * 8 + kk * 4 + g;
      bh8 a[4], bb[4];
      const u16* ap = qb + ((size_t)kc * MP + wrow + l15) * 8;
      #pragma unroll
      for (int mf = 0; mf < 4; ++mf) a[mf] = *(const bh8*)(ap + mf * 128);
      #pragma unroll
      for (int nf = 0; nf < 4; ++nf) bb[nf] = *(const bh8*)(kv + (nf * 16 + l15) * 264 + ko * 64 + kk * 32 + g * 8);
      #pragma unroll
      for (int mf = 0; mf < 4; ++mf)
        #pragma unroll
        for (int nf = 0; nf < 4; ++nf) acc[mf][nf] = MFMA(a[mf], bb[nf], acc[mf][nf]);
    }
  #pragma unroll
  for (int nf = 0; nf < 4; ++nf) if (!valid[nf]){
    #pragma unroll
    for (int mf = 0; mf < 4; ++mf){
      acc[mf][nf][0] = NEGV; acc[mf][nf][1] = NEGV; acc[mf][nf][2] = NEGV; acc[mf][nf][3] = NEGV;
    }
  }
  // per-strip softmax
  #pragma unroll
  for (int mf = 0; mf < 4; ++mf)
    #pragma unroll
    for (int r = 0; r < 4; ++r){
      float m0 = fmaxf(fmaxf(acc[mf][0][r], acc[mf][1][r]), fmaxf(acc[mf][2][r], acc[mf][3][r]));
      #pragma unroll
      for (int off = 1; off < 16; off <<= 1) m0 = fmaxf(m0, __shfl_xor(m0, off));
      int row = wrow + mf * 16 + 4 * g + r;
      float sum = 0.f;
      #pragma unroll
      for (int nf = 0; nf < 4; ++nf){
        float p = __expf(acc[mf][nf][r] - m0);
        sum += p;
        plds[row * 72 + nf * 16 + l15] = f2bf(p);
      }
      #pragma unroll
      for (int off = 1; off < 16; off <<= 1) sum += __shfl_xor(sum, off);
      if (l15 == 0){
        mrow[((size_t)b * NSTR + s) * MP + row] = m0;
        lrow[((size_t)b * NSTR + s) * MP + row] = sum;
      }
    }
  __syncthreads(); // all K reads done, P visible
  { // write V^T from regs with skewed layout (bank-conflict reduction)
    #pragma unroll
    for (int j = 0; j < 32; ++j){
      int d = dblk + j;
      kv[d * 88 + ((d >> 5) & 3) * 8 + key] = f2bf(vreg[j]);
    }
  }
  __syncthreads();
  // O_part = P V
  #pragma unroll
  for (int dc = 0; dc < 4; ++dc){
    f4 oc[4][4];
    #pragma unroll
    for (int i = 0; i < 4; ++i)
      #pragma unroll
      for (int j = 0; j < 4; ++j) oc[i][j] = (f4){0.f,0.f,0.f,0.f};
    #pragma unroll
    for (int kk = 0; kk < 2; ++kk){
      bh8 a[4], bb[4];
      #pragma unroll
      for (int mf = 0; mf < 4; ++mf) a[mf] = *(const bh8*)(plds + (wrow + mf * 16 + l15) * 72 + kk * 32 + g * 8);
      #pragma unroll
      for (int nf = 0; nf < 4; ++nf){
        int dcol = dc * 64 + nf * 16 + l15;
        bb[nf] = *(const bh8*)(kv + dcol * 88 + ((dcol >> 5) & 3) * 8 + kk * 32 + g * 8);
      }
      #pragma unroll
      for (int mf = 0; mf < 4; ++mf)
        #pragma unroll
        for (int nf = 0; nf < 4; ++nf) oc[mf][nf] = MFMA(a[mf], bb[nf], oc[mf][nf]);
    }
    #pragma unroll
    for (int mf = 0; mf < 4; ++mf)
      #pragma unroll
      for (int r = 0; r < 4; ++r){
        int row = wrow + mf * 16 + 4 * g + r;
        if (row < MR){
          #pragma unroll
          for (int nf = 0; nf < 4; ++nf){
            int d = dc * 64 + nf * 16 + l15;
            opart[(((size_t)b * NSTR + s) * MR + row) * HD + d] = f2bf(oc[mf][nf][r]);
          }
        }
      }
  }
}

// ---------------- combine strips -> attn_out fragA ----------------
__global__ void k_comb(const u16* __restrict__ opart, const float* __restrict__ mrow,
                       const float* __restrict__ lrow, u16* __restrict__ ao)
{
  int b = blockIdx.y;
  int d = threadIdx.x; // 256
  int r0 = blockIdx.x * 16;
  for (int i = 0; i < 16; ++i){
    int row = r0 + i;
    float M = -3.0e38f;
    for (int s2 = 0; s2 < NSTR; ++s2) M = fmaxf(M, mrow[((size_t)b * NSTR + s2) * MP + row]);
    float L = 0.f, o = 0.f;
    for (int s2 = 0; s2 < NSTR; ++s2){
      float w = __expf(mrow[((size_t)b * NSTR + s2) * MP + row] - M);
      L += w * lrow[((size_t)b * NSTR + s2) * MP + row];
      o += w * bf2f(opart[(((size_t)b * NSTR + s2) * MR + row) * HD + d]);
    }
    float val = o / L;
    int h = row / AHOR, tt = row - h * AHOR;
    int col = h * HD + d;
    int rg = b * AHOR + tt;
    ao[((size_t)(col >> 3)) * MP * 8 + (size_t)rg * 8 + (col & 7)] = f2bf(val);
  }
}

// ---------------- split-K GEMM -> bf16 partials (O-proj / MLP-down) ----------------
template<int NOUTER>
__global__ __launch_bounds__(512) void k_gemm_part(
    const u16* __restrict__ fa, const float* __restrict__ W, int wN,
    int kcPerSlice, u16* __restrict__ outp)
{
  __shared__ u16 lds[2 * 64 * 88];
  int n0 = blockIdx.x * 64;
  int ksl = blockIdx.y;
  f4 acc[4][4];
  #pragma unroll
  for (int i = 0; i < 4; ++i)
    #pragma unroll
    for (int j = 0; j < 4; ++j) acc[i][j] = (f4){0.f,0.f,0.f,0.f};
  gemm_core64<NOUTER>(fa, W, n0, W, n0 + 32, wN, ksl * kcPerSlice, lds, acc);
  int tid = threadIdx.x, lane = tid & 63, wave = tid >> 6, l15 = lane & 15, g = lane >> 4;
  int wrow = wave * 64;
  #pragma unroll
  for (int mf = 0; mf < 4; ++mf)
    #pragma unroll
    for (int r = 0; r < 4; ++r){
      int row = wrow + mf * 16 + 4 * g + r;
      #pragma unroll
      for (int nf = 0; nf < 4; ++nf)
        outp[((size_t)ksl * MP + row) * 1024 + n0 + nf * 16 + l15] = f2bf(acc[mf][nf][r]);
    }
}

// ---------------- MLP up: gelu(n2@Wg) * (n2@Wu) -> fragA ----------------
__global__ __launch_bounds__(512, 4) void k_mlpup(
    const u16* __restrict__ n2, const float* __restrict__ Wg, const float* __restrict__ Wu,
    u16* __restrict__ mlpf)
{
  __shared__ u16 lds[2 * 32 * 136];
  int n0 = blockIdx.x * 16;
  f4 acc[4][2];
  #pragma unroll
  for (int i = 0; i < 4; ++i)
    #pragma unroll
    for (int j = 0; j < 2; ++j) acc[i][j] = (f4){0.f,0.f,0.f,0.f};
  gemm_core32w<8>(n2, Wg, n0, Wu, n0, DMLP, lds, acc);
  int tid = threadIdx.x, lane = tid & 63, wave = tid >> 6, l15 = lane & 15, g = lane >> 4;
  int wrow = wave * 64;
  #pragma unroll
  for (int mf = 0; mf < 4; ++mf)
    #pragma unroll
    for (int r = 0; r < 4; ++r){
      int row = wrow + mf * 16 + 4 * g + r;
      int col = n0 + l15;
      float gg = acc[mf][0][r], uu = acc[mf][1][r];
      float act = geluf_(gg) * uu;
      mlpf[((size_t)(col >> 3)) * MP * 8 + (size_t)row * 8 + (col & 7)] = f2bf(act);
    }
}

// ---------------- final: out = nf @ W_act_out + b ----------------
__global__ void k_out(const u16* __restrict__ nfr, const float* __restrict__ W,
                      const float* __restrict__ bias, float* __restrict__ out)
{
  int t = threadIdx.x;
  int row = blockIdx.x * 8 + (t >> 5);
  int c = t & 31;
  float acc = bias[c];
  for (int k = 0; k < HIDN; ++k)
    acc += bf2f(nfr[((size_t)(k >> 3)) * MP * 8 + (size_t)row * 8 + (k & 7)]) * W[k * ADIMN + c];
  out[row * ADIMN + c] = acc;
}

extern "C" void kernel_launch(void* const* d_in, const int* in_sizes, int n_in,
                              void* d_out, int out_size, void* d_ws, size_t ws_size,
                              hipStream_t stream)
{
  const float* pk  = (const float*)d_in[0];
  const float* pv  = (const float*)d_in[1];
  const int*   msk = (const int*)d_in[2];
  const float* xt  = (const float*)d_in[3];
  const float* ts  = (const float*)d_in[4];
  const float* Wq  = (const float*)d_in[5];
  const float* Wk  = (const float*)d_in[6];
  const float* Wv  = (const float*)d_in[7];
  const float* Wo  = (const float*)d_in[8];
  const float* Wg  = (const float*)d_in[9];
  const float* Wu  = (const float*)d_in[10];
  const float* Wd  = (const float*)d_in[11];
  const float* A1  = (const float*)d_in[12];
  const float* A2  = (const float*)d_in[13];
  const float* Af  = (const float*)d_in[14];
  const float* Wai = (const float*)d_in[15];
  const float* bai = (const float*)d_in[16];
  const float* Wao = (const float*)d_in[17];
  const float* bao = (const float*)d_in[18];
  const float* Wti = (const float*)d_in[19];
  const float* bti = (const float*)d_in[20];
  const float* Wto = (const float*)d_in[21];
  const float* bto = (const float*)d_in[22];

  char* w = (char*)d_ws;
  size_t off = 0;
  auto alloc = [&](size_t bytes) -> char* {
    char* p = w + off; off += (bytes + 255) & ~(size_t)255; return p;
  };
  float* temb  = (float*)alloc((size_t)BATCH * HIDN * 4);
  float* ttmp  = (float*)alloc((size_t)BATCH * HIDN * 4);
  float* cond  = (float*)alloc((size_t)BATCH * HIDN * 4);
  int*   offs  = (int*)alloc(BATCH * 4);
  float* ropec = (float*)alloc((size_t)BATCH * AHOR * 128 * 4);
  float* ropes = (float*)alloc((size_t)BATCH * AHOR * 128 * 4);
  float* ada   = (float*)alloc((size_t)37 * 3 * BATCH * HIDN * 4);
  float* h     = (float*)alloc((size_t)MR * HIDN * 4);
  float* h1    = (float*)alloc((size_t)MR * HIDN * 4);
  u16*   n1    = (u16*)alloc((size_t)128 * MP * 8 * 2);
  u16*   n2    = (u16*)alloc((size_t)128 * MP * 8 * 2);
  u16*   qkvp  = (u16*)alloc((size_t)4 * MP * 2560 * 2);
  u16*   qf    = (u16*)alloc((size_t)BATCH * 32 * MP * 8 * 2);
  u16*   kss   = (u16*)alloc((size_t)BATCH * AHOR * HD * 2);
  u16*   vss   = (u16*)alloc((size_t)BATCH * AHOR * HD * 2);
  u16*   opart = (u16*)alloc((size_t)BATCH * NSTR * MR * HD * 2);
  float* mrow  = (float*)alloc((size_t)BATCH * NSTR * MP * 4);
  float* lrow  = (float*)alloc((size_t)BATCH * NSTR * MP * 4);
  u16*   ao    = (u16*)alloc((size_t)256 * MP * 8 * 2);
  u16*   opp   = (u16*)alloc((size_t)8 * MP * 1024 * 2);
  u16*   mlpf  = (u16*)alloc((size_t)512 * MP * 8 * 2);
  u16*   mdp   = (u16*)alloc((size_t)8 * MP * 1024 * 2);
  if (off > ws_size) return;

  k_prep<<<1, 256, 0, stream>>>(msk, ts, temb, offs, ropec, ropes);
  k_tproj<<<32, 256, 0, stream>>>(temb, Wti, bti, ttmp);
  k_tproj<<<32, 256, 0, stream>>>(ttmp, Wto, bto, cond);
  k_ada<<<dim3(3, 37), 256, 0, stream>>>(cond, A1, A2, Af, ada);
  k_hin<<<MR, 256, 0, stream>>>(xt, Wai, bai, h);

  auto AP = [&](int y, int comp){ return ada + ((size_t)y * 3 + comp) * BATCH * HIDN; };

  k_resnorm<<<128, 256, 0, stream>>>(0, 0, h, nullptr, nullptr, AP(0,0), AP(0,1), nullptr, n1);

  for (int l = 0; l < NLAY; ++l){
    k_qkv_part<<<dim3(40, 4), 512, 0, stream>>>(n1, Wq + (size_t)l * HIDN * NHEAD * HD,
                                                Wk + (size_t)l * HIDN * HD, Wv + (size_t)l * HIDN * HD, qkvp);
    k_qkv_rope<<<MR, 256, 0, stream>>>(qkvp, ropec, ropes, qf, kss, vss);
    k_attn<<<dim3(NSTR, BATCH), 512, 0, stream>>>(qf, kss, vss, pk, pv, msk, l, opart, mrow, lrow);
    k_comb<<<dim3(25, BATCH), 256, 0, stream>>>(opart, mrow, lrow, ao);
    k_gemm_part<4><<<dim3(16, 8), 512, 0, stream>>>(ao, Wo + (size_t)l * 2048 * 1024, 1024, 32, opp);
    k_resnorm<<<128, 256, 0, stream>>>(1, 8, h, opp, AP(l,2), AP(NLAY+l,0), AP(NLAY+l,1), h1, n2);
    k_mlpup<<<256, 512, 0, stream>>>(n2, Wg + (size_t)l * HIDN * DMLP, Wu + (size_t)l * HIDN * DMLP, mlpf);
    k_gemm_part<8><<<dim3(16, 8), 512, 0, stream>>>(mlpf, Wd + (size_t)l * DMLP * 1024, 1024, 64, mdp);
    const float* nsc = (l < NLAY - 1) ? AP(l + 1, 0) : AP(36, 0);
    const float* nsh = (l < NLAY - 1) ? AP(l + 1, 1) : AP(36, 1);
    k_resnorm<<<128, 256, 0, stream>>>(2, 8, h1, mdp, AP(NLAY+l,2), nsc, nsh, h, n1);
  }
  k_out<<<50, 256, 0, stream>>>(n1, Wao, bao, (float*)d_out);
}